// Round 11
// baseline (572.767 us; speedup 1.0000x reference)
//
#include <hip/hip_runtime.h>
#include <stdint.h>

// Problem constants: B=2, C=256, N=65536
#define NEDGE 65536

typedef __attribute__((ext_vector_type(4))) float f32x4;
typedef __attribute__((ext_vector_type(8))) __bf16 bf16x8;

#define VMCNT(n) asm volatile("s_waitcnt vmcnt(" #n ")" ::: "memory")
#define LGKM0 asm volatile("s_waitcnt lgkmcnt(0)" ::: "memory")
#define SCHEDB __builtin_amdgcn_sched_barrier(0)

__device__ __forceinline__ uint16_t f2bf(float f) {
  union { float f; uint32_t u; } v; v.f = f;
  uint32_t r = v.u + 0x7FFFu + ((v.u >> 16) & 1u);
  return (uint16_t)(r >> 16);
}
__device__ __forceinline__ float bflo(uint32_t u) {
  union { uint32_t u; float f; } v; v.u = u << 16; return v.f;
}
__device__ __forceinline__ float bfhi(uint32_t u) {
  union { uint32_t u; float f; } v; v.u = u & 0xFFFF0000u; return v.f;
}
__device__ __forceinline__ uint32_t packbf(float lo, float hi) {
  return (uint32_t)f2bf(lo) | ((uint32_t)f2bf(hi) << 16);
}
__device__ __forceinline__ void gload_lds16(const void* g, void* l) {
  __builtin_amdgcn_global_load_lds(
      (__attribute__((address_space(1))) uint32_t*)(uintptr_t)g,
      (__attribute__((address_space(3))) uint32_t*)l, 16, 0, 0);
}
__device__ __forceinline__ float sigm(float z) { return 1.0f / (1.0f + __expf(-z)); }

// ---------------- K0: weight composition ----------------
__global__ void k_compose(const float* __restrict__ Wal, const float* __restrict__ Wbl,
                          const float* __restrict__ Wat, const float* __restrict__ Wbt,
                          const float* __restrict__ Waf, const float* __restrict__ Wbf,
                          uint16_t* __restrict__ Wt) {
  int id = blockIdx.x * 256 + threadIdx.x;
  if (id >= 512 * 640) return;
  int j = id / 640, kk = id % 640;
  const float* Wf = (j < 256) ? Waf : Wbf;
  const float* Wl = (j < 256) ? Wal : Wbl;
  const float* Wr = (j < 256) ? Wat : Wbt;
  int jj = j & 255;
  float acc = 0.f;
  if (kk < 128) {
    int c = kk;
    for (int o = 0; o < 128; ++o) acc += Wl[o * 128 + c] * Wf[jj * 256 + o];
    for (int o = 0; o < 128; ++o) acc += Wr[(o * 128 + c) * 5 + 0] * Wf[jj * 256 + 128 + o];
  } else {
    int blkid = (kk - 128) >> 7;
    int gk = (blkid == 0) ? 1 : (blkid == 1) ? 3 : (blkid == 2) ? 2 : 4;
    int c = (kk - 128) & 127;
    for (int o = 0; o < 128; ++o) acc += Wr[(o * 128 + c) * 5 + gk] * Wf[jj * 256 + 128 + o];
  }
  Wt[j * 640 + kk] = f2bf(acc);
}

__global__ void k_bias(const float* __restrict__ bal, const float* __restrict__ bat,
                       const float* __restrict__ baf, const float* __restrict__ bbl,
                       const float* __restrict__ bbt, const float* __restrict__ bbf,
                       const float* __restrict__ Waf, const float* __restrict__ Wbf,
                       float* __restrict__ biasF) {
  int id = blockIdx.x * 256 + threadIdx.x;
  if (id >= 512) return;
  const float* Wf = (id < 256) ? Waf : Wbf;
  const float* bl = (id < 256) ? bal : bbl;
  const float* bt = (id < 256) ? bat : bbt;
  const float* bsf = (id < 256) ? baf : bbf;
  int jj = id & 255;
  float acc = bsf[jj];
  for (int o = 0; o < 128; ++o) acc += Wf[jj * 256 + o] * bl[o];
  for (int o = 0; o < 128; ++o) acc += Wf[jj * 256 + 128 + o] * bt[o];
  biasF[id] = acc;
}

// First-layer weights -> bf16, [side][j][c] row-major
__global__ void k_wt1(const float* __restrict__ Wa, const float* __restrict__ Wb,
                      uint16_t* __restrict__ W1bf) {
  int id = blockIdx.x * 256 + threadIdx.x;
  if (id >= 2 * 64 * 256) return;
  int side = id >> 14, r = id & 16383;
  W1bf[id] = f2bf(side ? Wb[r] : Wa[r]);
}

// ---------------- K1: XA = [Wa@x0+ba | Wb@x1+bb] (R10, unchanged) ----------------
__global__ __launch_bounds__(256) void k1_xa(
    const float* __restrict__ x0, const float* __restrict__ x1,
    const uint16_t* __restrict__ W1bf, const float* __restrict__ ba,
    const float* __restrict__ bb, uint16_t* __restrict__ XA) {
  __shared__ __align__(16) float Xs[3][32 * 128];    // 3 x 16 KB
  __shared__ __align__(16) uint16_t Bs[64 * 256];    // 32 KB
  int t = threadIdx.x;
  int L = blockIdx.x;
  int xcd = L & 7, jj = L >> 3;
  int ntile = xcd * 64 + (jj & 63);
  int sideb = jj >> 6;
  int side = sideb & 1, b = sideb >> 1;
  int n0 = ntile * 128;
  const float* xin = (side ? x1 : x0) + (size_t)b * 256 * NEDGE + n0;
  const uint16_t* wsrc = W1bf + side * 64 * 256;

#pragma unroll
  for (int q = 0; q < 8; ++q) {
    int s = q * 256 + t;
    int j = s >> 5, pb = s & 31;
    int lb = pb ^ (j & 7);
    gload_lds16(wsrc + j * 256 + lb * 8, &Bs[s * 8]);
  }
#pragma unroll
  for (int c = 0; c < 2; ++c) {
#pragma unroll
    for (int q = 0; q < 4; ++q) {
      int s = q * 256 + t;
      int cl = s >> 5, pb = s & 31;
      int lb = pb ^ (((cl >> 3) & 3) << 2);
      gload_lds16(xin + (size_t)(c * 32 + cl) * NEDGE + lb * 4, &Xs[c][s * 4]);
    }
  }

  int wv = t >> 6, l = t & 63;
  int m = l & 15, g = l >> 4;
  int pcol[2];
#pragma unroll
  for (int nf = 0; nf < 2; ++nf) {
    int n = wv * 32 + nf * 16 + m;
    pcol[nf] = (((n >> 2) ^ (g << 2)) << 2) + (n & 3);
  }

  f32x4 acc[2][4];
  f32x4 zero = {0.f, 0.f, 0.f, 0.f};
#pragma unroll
  for (int nf = 0; nf < 2; ++nf)
#pragma unroll
    for (int jf = 0; jf < 4; ++jf) acc[nf][jf] = zero;

#pragma unroll
  for (int ks = 0; ks < 8; ++ks) {
    if (ks < 6) {
      const float* xc = xin + (size_t)(ks + 2) * 32 * NEDGE;
#pragma unroll
      for (int q = 0; q < 4; ++q) {
        int s = q * 256 + t;
        int cl = s >> 5, pb = s & 31;
        int lb = pb ^ (((cl >> 3) & 3) << 2);
        gload_lds16(xc + (size_t)cl * NEDGE + lb * 4, &Xs[(ks + 2) % 3][s * 4]);
      }
      VMCNT(8);
    } else if (ks == 6) {
      VMCNT(4);
    } else {
      VMCNT(0);
    }
    SCHEDB;
    __builtin_amdgcn_s_barrier();
    SCHEDB;

    const float* Xb = Xs[ks % 3];
    bf16x8 af[4];
#pragma unroll
    for (int jf = 0; jf < 4; ++jf) {
      int jloc = jf * 16 + m;
      int pbb = (ks * 4 + g) ^ (jloc & 7);
      af[jf] = *(const bf16x8*)&Bs[jloc * 256 + pbb * 8];
    }
#pragma unroll
    for (int nf = 0; nf < 2; ++nf) {
      const float* base = Xb + g * 8 * 128 + pcol[nf];
      float xv[8];
#pragma unroll
      for (int i = 0; i < 8; ++i) xv[i] = base[i * 128];
      union { bf16x8 v; uint32_t u[4]; } bx;
      bx.u[0] = packbf(xv[0], xv[1]);
      bx.u[1] = packbf(xv[2], xv[3]);
      bx.u[2] = packbf(xv[4], xv[5]);
      bx.u[3] = packbf(xv[6], xv[7]);
#pragma unroll
      for (int jf = 0; jf < 4; ++jf)
        acc[nf][jf] = __builtin_amdgcn_mfma_f32_16x16x32_bf16(af[jf], bx.v, acc[nf][jf], 0, 0, 0);
    }
    LGKM0;
    __builtin_amdgcn_s_barrier();
    SCHEDB;
  }

  const float* bias = side ? bb : ba;
  uint16_t* XAb = XA + (size_t)b * NEDGE * 128;
#pragma unroll
  for (int jf = 0; jf < 4; ++jf) {
    f32x4 bv = *(const f32x4*)(bias + jf * 16 + g * 4);
#pragma unroll
    for (int nf = 0; nf < 2; ++nf) {
      int n = n0 + wv * 32 + nf * 16 + m;
      uint2 o;
      o.x = packbf(acc[nf][jf][0] + bv[0], acc[nf][jf][1] + bv[1]);
      o.y = packbf(acc[nf][jf][2] + bv[2], acc[nf][jf][3] + bv[3]);
      *(uint2*)(XAb + (size_t)n * 128 + side * 64 + jf * 16 + g * 4) = o;
    }
  }
}

// ---------------- K23: fused gather+features+GEMM+stats, BK=32 deep pipeline ----
// 20 K-steps of 32. As[2] 8KB each, Bs[2] 16KB each, gi 2KB => 50KB -> 3 blk/CU.
// Everything issued >=1 iter ahead; gathers double-reg-banked, 2 iters ahead.
__global__ __launch_bounds__(512) void k23_gemm(
    const uint16_t* __restrict__ XAb, const int* __restrict__ gidx,
    const uint16_t* __restrict__ Wt, const float* __restrict__ biasF,
    uint16_t* __restrict__ Y, float* __restrict__ part) {
  __shared__ __align__(16) uint16_t As[2][128 * 32];    // 2 x 8 KB
  __shared__ __align__(16) uint16_t Bs[2][256 * 32];    // 2 x 16 KB
  __shared__ int gi[512];                               // 2 KB
  int t = threadIdx.x;
  int L = blockIdx.x;
  int xcd = L & 7, jz = L >> 3;
  int bx = xcd * 64 + (jz >> 1);
  int jbase = (jz & 1) * 256;
  int ebase = bx * 128;
  int wid = t >> 6, lane = t & 63;
  int wr = wid >> 2, wc = wid & 3;
  int m = lane & 15, g = lane >> 4;

  gi[t] = gidx[(size_t)ebase * 4 + t];
  __syncthreads();

  const int r0 = t >> 3, cc = t & 7;
  int iP13[2], iQ13[2], iP24[2], iQ24[2];
#pragma unroll
  for (int q2 = 0; q2 < 2; ++q2) {
    int r = r0 + q2 * 64;
    iP13[q2] = gi[r * 4 + 0]; iQ13[q2] = gi[r * 4 + 2];
    iP24[q2] = gi[r * 4 + 1]; iQ24[q2] = gi[r * 4 + 3];
  }

  uint4 grP[2][2], grQ[2][2];   // [bank v&1][q2]

#define ISSUE_ASD(u_)                                                           \
  do {                                                                          \
    int r = t >> 2, cb = t & 3;                                                 \
    gload_lds16(XAb + (size_t)(ebase + r) * 128 + (u_) * 32 + ((cb ^ (r & 3)) * 8), \
                &As[(u_) & 1][t * 8]);                                          \
  } while (0)

#define ISSUE_BSC(u_)                                                           \
  do {                                                                          \
    _Pragma("unroll")                                                           \
    for (int q = 0; q < 2; ++q) {                                               \
      int s = q * 512 + t; int r = s >> 2, cb = s & 3;                          \
      gload_lds16(Wt + (size_t)(jbase + r) * 640 + (u_) * 32 + ((cb ^ (r & 3)) * 8), \
                  &Bs[(u_) & 1][s * 8]);                                        \
    }                                                                           \
  } while (0)

#define ISSUE_G(v_)                                                             \
  do {                                                                          \
    const int coffv = ((v_) & 1) * 64;                                          \
    const int pr = ((v_) - 2) >> 2;                                             \
    const int bk = (v_) & 1;                                                    \
    _Pragma("unroll")                                                           \
    for (int q2 = 0; q2 < 2; ++q2) {                                            \
      int ip = pr ? iP24[q2] : iP13[q2];                                        \
      int iq = pr ? iQ24[q2] : iQ13[q2];                                        \
      grP[bk][q2] = *(const uint4*)(XAb + (size_t)ip * 128 + coffv + cc * 8);   \
      grQ[bk][q2] = *(const uint4*)(XAb + (size_t)iq * 128 + coffv + cc * 8);   \
    }                                                                           \
  } while (0)

#define FEAT(v_, h_, u_)                                                        \
  do {                                                                          \
    if ((cc >> 2) == (h_)) {                                                    \
      const int bk = (v_) & 1;                                                  \
      const bool sum_op = ((((v_) - 2) >> 1) & 1) == 0;                         \
      _Pragma("unroll")                                                         \
      for (int q2 = 0; q2 < 2; ++q2) {                                          \
        int r = r0 + q2 * 64;                                                   \
        uint4 P = grP[bk][q2], Q = grQ[bk][q2];                                 \
        uint4 R;                                                                \
        if (sum_op) {                                                           \
          R.x = packbf(bflo(P.x) + bflo(Q.x), bfhi(P.x) + bfhi(Q.x));           \
          R.y = packbf(bflo(P.y) + bflo(Q.y), bfhi(P.y) + bfhi(Q.y));           \
          R.z = packbf(bflo(P.z) + bflo(Q.z), bfhi(P.z) + bfhi(Q.z));           \
          R.w = packbf(bflo(P.w) + bflo(Q.w), bfhi(P.w) + bfhi(Q.w));           \
        } else {                                                                \
          R.x = packbf(fabsf(bflo(P.x) - bflo(Q.x)), fabsf(bfhi(P.x) - bfhi(Q.x))); \
          R.y = packbf(fabsf(bflo(P.y) - bflo(Q.y)), fabsf(bfhi(P.y) - bfhi(Q.y))); \
          R.z = packbf(fabsf(bflo(P.z) - bflo(Q.z)), fabsf(bfhi(P.z) - bfhi(Q.z))); \
          R.w = packbf(fabsf(bflo(P.w) - bflo(Q.w)), fabsf(bfhi(P.w) - bfhi(Q.w))); \
        }                                                                       \
        *(uint4*)&As[(u_) & 1][(r * 4 + ((cc & 3) ^ (r & 3))) * 8] = R;         \
      }                                                                         \
    }                                                                           \
  } while (0)

  // prologue: A0, B0, A1, B1 (in this order for the vmcnt ledger)
  ISSUE_ASD(0);
  ISSUE_BSC(0);
  ISSUE_ASD(1);
  ISSUE_BSC(1);

  f32x4 acc[4][4];
  f32x4 zero = {0.f, 0.f, 0.f, 0.f};
#pragma unroll
  for (int r = 0; r < 4; ++r)
#pragma unroll
    for (int c = 0; c < 4; ++c) acc[r][c] = zero;

#pragma unroll
  for (int u = 0; u < 20; ++u) {
    if (u == 0) {
      VMCNT(3);
    } else if (u == 1) {
      ISSUE_ASD(2); ISSUE_BSC(2);
      VMCNT(3);
    } else if (u == 2) {
      ISSUE_ASD(3); ISSUE_BSC(3); ISSUE_G(2);
      VMCNT(7);
    } else if (u == 3) {
      ISSUE_BSC(4);
      VMCNT(6);
    } else if (u <= 17 && (u & 1) == 0) {
      VMCNT(2);           // retire G(u/2)
      SCHEDB;
      FEAT(u >> 1, 0, u);
      ISSUE_BSC(u + 1);
      ISSUE_G((u >> 1) + 1);
      VMCNT(6);           // retire Bs(u), keep Bs(u+1)+G
    } else if (u <= 17) {
      FEAT(u >> 1, 1, u);
      ISSUE_BSC(u + 1);
      VMCNT(6);           // retire Bs(u), keep G+Bs(u+1)
    } else if (u == 18) {
      VMCNT(2);           // retire G(9)
      SCHEDB;
      FEAT(9, 0, 18);
      ISSUE_BSC(19);
      VMCNT(2);           // retire Bs(18), keep Bs(19)
    } else {
      FEAT(9, 1, 19);
      VMCNT(0);
    }
    LGKM0;
    SCHEDB;
    __builtin_amdgcn_s_barrier();
    SCHEDB;

    const uint16_t* Ab = As[u & 1];
    const uint16_t* Bb = Bs[u & 1];
    bf16x8 af[4], bf[4];
#pragma unroll
    for (int r = 0; r < 4; ++r) {
      int row = wr * 64 + r * 16 + m;
      af[r] = *(const bf16x8*)&Ab[(row * 4 + (g ^ (m & 3))) * 8];
    }
#pragma unroll
    for (int cf = 0; cf < 4; ++cf) {
      int row = wc * 64 + cf * 16 + m;
      bf[cf] = *(const bf16x8*)&Bb[(row * 4 + (g ^ (m & 3))) * 8];
    }
#pragma unroll
    for (int r = 0; r < 4; ++r)
#pragma unroll
      for (int cf = 0; cf < 4; ++cf)
        acc[r][cf] = __builtin_amdgcn_mfma_f32_16x16x32_bf16(bf[cf], af[r], acc[r][cf], 0, 0, 0);
    __builtin_amdgcn_s_barrier();
    SCHEDB;
  }
#undef ISSUE_ASD
#undef ISSUE_BSC
#undef ISSUE_G
#undef FEAT

  // epilogue: D[j][edge]: lane&15 = edge, regs = 4 consecutive j (g*4+q)
  float s1[4][4], s2[4][4];
#pragma unroll
  for (int cf = 0; cf < 4; ++cf)
#pragma unroll
    for (int q = 0; q < 4; ++q) { s1[cf][q] = 0.f; s2[cf][q] = 0.f; }

#pragma unroll
  for (int cf = 0; cf < 4; ++cf) {
    f32x4 bv = *(const f32x4*)(biasF + jbase + wc * 64 + cf * 16 + g * 4);
#pragma unroll
    for (int r = 0; r < 4; ++r) {
      int eg = ebase + wr * 64 + r * 16 + m;
      float v0 = acc[r][cf][0] + bv[0];
      float v1 = acc[r][cf][1] + bv[1];
      float v2 = acc[r][cf][2] + bv[2];
      float v3 = acc[r][cf][3] + bv[3];
      s1[cf][0] += v0; s2[cf][0] += v0 * v0;
      s1[cf][1] += v1; s2[cf][1] += v1 * v1;
      s1[cf][2] += v2; s2[cf][2] += v2 * v2;
      s1[cf][3] += v3; s2[cf][3] += v3 * v3;
      uint2 o;
      o.x = packbf(v0, v1);
      o.y = packbf(v2, v3);
      *(uint2*)(Y + (size_t)eg * 512 + jbase + wc * 64 + cf * 16 + g * 4) = o;
    }
  }
#pragma unroll
  for (int cf = 0; cf < 4; ++cf)
#pragma unroll
    for (int q = 0; q < 4; ++q) {
#pragma unroll
      for (int off = 1; off < 16; off <<= 1) {
        s1[cf][q] += __shfl_xor(s1[cf][q], off);
        s2[cf][q] += __shfl_xor(s2[cf][q], off);
      }
    }
  if (m == 0) {
#pragma unroll
    for (int cf = 0; cf < 4; ++cf)
#pragma unroll
      for (int q = 0; q < 4; ++q) {
        int jl = wc * 64 + cf * 16 + g * 4 + q;
        float* p = part + (((size_t)bx * 2 + wr) * 512 + jbase + jl) * 2;
        p[0] = s1[cf][q];
        p[1] = s2[cf][q];
      }
  }
}

// ---------------- K3b2: finalize per-column mean/rsqrt (1024 partials) ----------
__global__ void k3b2(const float* __restrict__ part, float* __restrict__ statF) {
  int col = blockIdx.x, t = threadIdx.x;
  float s1 = 0, s2 = 0;
  for (int k = t; k < 1024; k += 128) {
    const float* p = part + ((size_t)k * 512 + col) * 2;
    s1 += p[0]; s2 += p[1];
  }
  for (int off = 32; off; off >>= 1) { s1 += __shfl_down(s1, off); s2 += __shfl_down(s2, off); }
  __shared__ float sh[4];
  if ((t & 63) == 0) { sh[(t >> 6) * 2] = s1; sh[(t >> 6) * 2 + 1] = s2; }
  __syncthreads();
  if (t == 0) {
    s1 = sh[0] + sh[2]; s2 = sh[1] + sh[3];
    float mean = s1 * (1.0f / 65536.0f);
    float var = s2 * (1.0f / 65536.0f) - mean * mean;
    statF[col * 2] = mean;
    statF[col * 2 + 1] = rsqrtf(var + 1e-5f);
  }
}

// ---------------- K4: gate + blend, channel-major out (R10, unchanged) ----------
__global__ __launch_bounds__(256) void k4_final(
    const uint16_t* __restrict__ Y, const float* __restrict__ statF,
    const float* __restrict__ x0b, const float* __restrict__ x1b,
    float* __restrict__ outb) {
  __shared__ float W0[128][65];
  __shared__ float mA[128], rA[128], mB[128], rB[128];
  int t = threadIdx.x;
  int L = blockIdx.x;
  int xcd = L & 7, jz = L >> 3;
  int n0 = (xcd * 128 + (jz >> 1)) * 64;
  int ch = jz & 1;
  if (t < 128) {
    mA[t] = statF[(ch * 128 + t) * 2];
    rA[t] = statF[(ch * 128 + t) * 2 + 1];
  } else {
    int q = t - 128;
    mB[q] = statF[(256 + ch * 128 + q) * 2];
    rB[q] = statF[(256 + ch * 128 + q) * 2 + 1];
  }
  __syncthreads();
  const char* Ybase = (const char*)Y;
  for (int i = t; i < 64 * 64; i += 256) {
    int row = i >> 6, cp = i & 63;
    const char* yr = Ybase + (size_t)(n0 + row) * 1024;
    uint32_t ya2 = *(const uint32_t*)(yr + ch * 256 + cp * 4);
    uint32_t yb2 = *(const uint32_t*)(yr + 512 + ch * 256 + cp * 4);
    int c0 = 2 * cp, c1 = 2 * cp + 1;
    float wa0 = sigm((bflo(ya2) - mA[c0]) * rA[c0]);
    float wa1 = sigm((bfhi(ya2) - mA[c1]) * rA[c1]);
    float wb0 = sigm((bflo(yb2) - mB[c0]) * rB[c0]);
    float wb1 = sigm((bfhi(yb2) - mB[c1]) * rB[c1]);
    W0[c0][row] = sigm(wa0 - wb0);
    W0[c1][row] = sigm(wa1 - wb1);
  }
  __syncthreads();
  int nn = t & 63, cg = t >> 6;
  for (int cc2 = cg; cc2 < 128; cc2 += 4) {
    int c = ch * 128 + cc2;
    size_t gidx2 = (size_t)c * NEDGE + n0 + nn;
    float w0 = W0[cc2][nn];
    outb[gidx2] = x0b[gidx2] * w0 + x1b[gidx2] * (1.0f - w0);
  }
}

extern "C" void kernel_launch(void* const* d_in, const int* in_sizes, int n_in,
                              void* d_out, int out_size, void* d_ws, size_t ws_size,
                              hipStream_t stream) {
  const float* x0 = (const float*)d_in[0];
  const float* x1 = (const float*)d_in[1];
  const int* gemm = (const int*)d_in[2];
  const float* Wa = (const float*)d_in[3];
  const float* ba = (const float*)d_in[4];
  const float* Wb = (const float*)d_in[5];
  const float* bb = (const float*)d_in[6];
  const float* Wal = (const float*)d_in[7];
  const float* bal = (const float*)d_in[8];
  const float* Wbl = (const float*)d_in[9];
  const float* bbl = (const float*)d_in[10];
  const float* Wat = (const float*)d_in[11];
  const float* bat = (const float*)d_in[12];
  const float* Wbt = (const float*)d_in[13];
  const float* bbt = (const float*)d_in[14];
  const float* Waf = (const float*)d_in[15];
  const float* baf = (const float*)d_in[16];
  const float* Wbf = (const float*)d_in[17];
  const float* bbf = (const float*)d_in[18];
  float* out = (float*)d_out;

  char* ws = (char*)d_ws;
  uint16_t* XA   = (uint16_t*)ws;                    // 33,554,432 B
  uint16_t* Yb   = (uint16_t*)(ws + 33554432);       // 67,108,864 B (per-batch reuse)
  uint16_t* Wt   = (uint16_t*)(ws + 100663296);      // 655,360 B
  uint16_t* W1bf = (uint16_t*)(ws + 101318656);      // 65,536 B
  float*    biasF= (float*)(ws + 101384192);         // 2,048 B
  float*    part = (float*)(ws + 101386240);         // 4,194,304 B (per-batch reuse)
  float*    statF= (float*)(ws + 105580544);         // 8,192 B

  k_compose<<<dim3(1280), dim3(256), 0, stream>>>(Wal, Wbl, Wat, Wbt, Waf, Wbf, Wt);
  k_bias<<<dim3(2), dim3(256), 0, stream>>>(bal, bat, baf, bbl, bbt, bbf, Waf, Wbf, biasF);
  k_wt1<<<dim3(128), dim3(256), 0, stream>>>(Wa, Wb, W1bf);
  k1_xa<<<dim3(2048), dim3(256), 0, stream>>>(x0, x1, W1bf, ba, bb, XA);

  for (int b = 0; b < 2; ++b) {
    const uint16_t* XAb = XA + (size_t)b * NEDGE * 128;
    k23_gemm<<<dim3(1024), dim3(512), 0, stream>>>(
        XAb, gemm + (size_t)b * NEDGE * 4, Wt, biasF, Yb, part);
    k3b2<<<dim3(512), dim3(128), 0, stream>>>(part, statF + b * 1024);
    k4_final<<<dim3(2048), dim3(256), 0, stream>>>(
        Yb, statF + b * 1024, x0 + (size_t)b * 256 * NEDGE,
        x1 + (size_t)b * 256 * NEDGE, out + (size_t)b * 256 * NEDGE);
  }
}

// Round 12
// 501.352 us; speedup vs baseline: 1.1424x; 1.1424x over previous
//
#include <hip/hip_runtime.h>
#include <stdint.h>

// Problem constants: B=2, C=256, N=65536
#define NEDGE 65536

typedef __attribute__((ext_vector_type(4))) float f32x4;
typedef __attribute__((ext_vector_type(8))) __bf16 bf16x8;

#define VMCNT(n) asm volatile("s_waitcnt vmcnt(" #n ")" ::: "memory")
#define LGKM0 asm volatile("s_waitcnt lgkmcnt(0)" ::: "memory")
#define SCHEDB __builtin_amdgcn_sched_barrier(0)

__device__ __forceinline__ uint16_t f2bf(float f) {
  union { float f; uint32_t u; } v; v.f = f;
  uint32_t r = v.u + 0x7FFFu + ((v.u >> 16) & 1u);
  return (uint16_t)(r >> 16);
}
__device__ __forceinline__ float bflo(uint32_t u) {
  union { uint32_t u; float f; } v; v.u = u << 16; return v.f;
}
__device__ __forceinline__ float bfhi(uint32_t u) {
  union { uint32_t u; float f; } v; v.u = u & 0xFFFF0000u; return v.f;
}
__device__ __forceinline__ uint32_t packbf(float lo, float hi) {
  return (uint32_t)f2bf(lo) | ((uint32_t)f2bf(hi) << 16);
}
__device__ __forceinline__ void gload_lds16(const void* g, void* l) {
  __builtin_amdgcn_global_load_lds(
      (__attribute__((address_space(1))) uint32_t*)(uintptr_t)g,
      (__attribute__((address_space(3))) uint32_t*)l, 16, 0, 0);
}
__device__ __forceinline__ uint4 gload16(const void* p) {
  uint4 d;
  asm volatile("global_load_dwordx4 %0, %1, off" : "=v"(d) : "v"(p));
  return d;
}
__device__ __forceinline__ float sigm(float z) { return 1.0f / (1.0f + __expf(-z)); }

// ---------------- K0: weight composition ----------------
__global__ void k_compose(const float* __restrict__ Wal, const float* __restrict__ Wbl,
                          const float* __restrict__ Wat, const float* __restrict__ Wbt,
                          const float* __restrict__ Waf, const float* __restrict__ Wbf,
                          uint16_t* __restrict__ Wt) {
  int id = blockIdx.x * 256 + threadIdx.x;
  if (id >= 512 * 640) return;
  int j = id / 640, kk = id % 640;
  const float* Wf = (j < 256) ? Waf : Wbf;
  const float* Wl = (j < 256) ? Wal : Wbl;
  const float* Wr = (j < 256) ? Wat : Wbt;
  int jj = j & 255;
  float acc = 0.f;
  if (kk < 128) {
    int c = kk;
    for (int o = 0; o < 128; ++o) acc += Wl[o * 128 + c] * Wf[jj * 256 + o];
    for (int o = 0; o < 128; ++o) acc += Wr[(o * 128 + c) * 5 + 0] * Wf[jj * 256 + 128 + o];
  } else {
    int blkid = (kk - 128) >> 7;
    int gk = (blkid == 0) ? 1 : (blkid == 1) ? 3 : (blkid == 2) ? 2 : 4;
    int c = (kk - 128) & 127;
    for (int o = 0; o < 128; ++o) acc += Wr[(o * 128 + c) * 5 + gk] * Wf[jj * 256 + 128 + o];
  }
  Wt[j * 640 + kk] = f2bf(acc);
}

__global__ void k_bias(const float* __restrict__ bal, const float* __restrict__ bat,
                       const float* __restrict__ baf, const float* __restrict__ bbl,
                       const float* __restrict__ bbt, const float* __restrict__ bbf,
                       const float* __restrict__ Waf, const float* __restrict__ Wbf,
                       float* __restrict__ biasF) {
  int id = blockIdx.x * 256 + threadIdx.x;
  if (id >= 512) return;
  const float* Wf = (id < 256) ? Waf : Wbf;
  const float* bl = (id < 256) ? bal : bbl;
  const float* bt = (id < 256) ? bat : bbt;
  const float* bsf = (id < 256) ? baf : bbf;
  int jj = id & 255;
  float acc = bsf[jj];
  for (int o = 0; o < 128; ++o) acc += Wf[jj * 256 + o] * bl[o];
  for (int o = 0; o < 128; ++o) acc += Wf[jj * 256 + 128 + o] * bt[o];
  biasF[id] = acc;
}

// First-layer weights -> bf16, [side][j][c] row-major
__global__ void k_wt1(const float* __restrict__ Wa, const float* __restrict__ Wb,
                      uint16_t* __restrict__ W1bf) {
  int id = blockIdx.x * 256 + threadIdx.x;
  if (id >= 2 * 64 * 256) return;
  int side = id >> 14, r = id & 16383;
  W1bf[id] = f2bf(side ? Wb[r] : Wa[r]);
}

// ---------------- K1: XA = [Wa@x0+ba | Wb@x1+bb] (R10, unchanged) ----------------
__global__ __launch_bounds__(256) void k1_xa(
    const float* __restrict__ x0, const float* __restrict__ x1,
    const uint16_t* __restrict__ W1bf, const float* __restrict__ ba,
    const float* __restrict__ bb, uint16_t* __restrict__ XA) {
  __shared__ __align__(16) float Xs[3][32 * 128];    // 3 x 16 KB
  __shared__ __align__(16) uint16_t Bs[64 * 256];    // 32 KB
  int t = threadIdx.x;
  int L = blockIdx.x;
  int xcd = L & 7, jj = L >> 3;
  int ntile = xcd * 64 + (jj & 63);
  int sideb = jj >> 6;
  int side = sideb & 1, b = sideb >> 1;
  int n0 = ntile * 128;
  const float* xin = (side ? x1 : x0) + (size_t)b * 256 * NEDGE + n0;
  const uint16_t* wsrc = W1bf + side * 64 * 256;

#pragma unroll
  for (int q = 0; q < 8; ++q) {
    int s = q * 256 + t;
    int j = s >> 5, pb = s & 31;
    int lb = pb ^ (j & 7);
    gload_lds16(wsrc + j * 256 + lb * 8, &Bs[s * 8]);
  }
#pragma unroll
  for (int c = 0; c < 2; ++c) {
#pragma unroll
    for (int q = 0; q < 4; ++q) {
      int s = q * 256 + t;
      int cl = s >> 5, pb = s & 31;
      int lb = pb ^ (((cl >> 3) & 3) << 2);
      gload_lds16(xin + (size_t)(c * 32 + cl) * NEDGE + lb * 4, &Xs[c][s * 4]);
    }
  }

  int wv = t >> 6, l = t & 63;
  int m = l & 15, g = l >> 4;
  int pcol[2];
#pragma unroll
  for (int nf = 0; nf < 2; ++nf) {
    int n = wv * 32 + nf * 16 + m;
    pcol[nf] = (((n >> 2) ^ (g << 2)) << 2) + (n & 3);
  }

  f32x4 acc[2][4];
  f32x4 zero = {0.f, 0.f, 0.f, 0.f};
#pragma unroll
  for (int nf = 0; nf < 2; ++nf)
#pragma unroll
    for (int jf = 0; jf < 4; ++jf) acc[nf][jf] = zero;

#pragma unroll
  for (int ks = 0; ks < 8; ++ks) {
    if (ks < 6) {
      const float* xc = xin + (size_t)(ks + 2) * 32 * NEDGE;
#pragma unroll
      for (int q = 0; q < 4; ++q) {
        int s = q * 256 + t;
        int cl = s >> 5, pb = s & 31;
        int lb = pb ^ (((cl >> 3) & 3) << 2);
        gload_lds16(xc + (size_t)cl * NEDGE + lb * 4, &Xs[(ks + 2) % 3][s * 4]);
      }
      VMCNT(8);
    } else if (ks == 6) {
      VMCNT(4);
    } else {
      VMCNT(0);
    }
    SCHEDB;
    __builtin_amdgcn_s_barrier();
    SCHEDB;

    const float* Xb = Xs[ks % 3];
    bf16x8 af[4];
#pragma unroll
    for (int jf = 0; jf < 4; ++jf) {
      int jloc = jf * 16 + m;
      int pbb = (ks * 4 + g) ^ (jloc & 7);
      af[jf] = *(const bf16x8*)&Bs[jloc * 256 + pbb * 8];
    }
#pragma unroll
    for (int nf = 0; nf < 2; ++nf) {
      const float* base = Xb + g * 8 * 128 + pcol[nf];
      float xv[8];
#pragma unroll
      for (int i = 0; i < 8; ++i) xv[i] = base[i * 128];
      union { bf16x8 v; uint32_t u[4]; } bx;
      bx.u[0] = packbf(xv[0], xv[1]);
      bx.u[1] = packbf(xv[2], xv[3]);
      bx.u[2] = packbf(xv[4], xv[5]);
      bx.u[3] = packbf(xv[6], xv[7]);
#pragma unroll
      for (int jf = 0; jf < 4; ++jf)
        acc[nf][jf] = __builtin_amdgcn_mfma_f32_16x16x32_bf16(af[jf], bx.v, acc[nf][jf], 0, 0, 0);
    }
    LGKM0;
    __builtin_amdgcn_s_barrier();
    SCHEDB;
  }

  const float* bias = side ? bb : ba;
  uint16_t* XAb = XA + (size_t)b * NEDGE * 128;
#pragma unroll
  for (int jf = 0; jf < 4; ++jf) {
    f32x4 bv = *(const f32x4*)(bias + jf * 16 + g * 4);
#pragma unroll
    for (int nf = 0; nf < 2; ++nf) {
      int n = n0 + wv * 32 + nf * 16 + m;
      uint2 o;
      o.x = packbf(acc[nf][jf][0] + bv[0], acc[nf][jf][1] + bv[1]);
      o.y = packbf(acc[nf][jf][2] + bv[2], acc[nf][jf][3] + bv[3]);
      *(uint2*)(XAb + (size_t)n * 128 + side * 64 + jf * 16 + g * 4) = o;
    }
  }
}

// ---------------- K23: fused gather+features+GEMM+stats ----------------
// R8 structure (register-staged Wt, no Bs LDS, 1 barrier/iter) with the bounds
// fix: __launch_bounds__(512, 2) -> VGPR cap 128 (R8's (512,4) forced cap 64 and
// spilled everything). LDS 38 KB. XCD-bijective swizzle from R10.
__global__ __launch_bounds__(512, 2) void k23_gemm(
    const uint16_t* __restrict__ XAb, const int* __restrict__ gidx,
    const uint16_t* __restrict__ Wt, const float* __restrict__ biasF,
    uint16_t* __restrict__ Y, float* __restrict__ part) {
  __shared__ __align__(16) uint16_t As[2][128 * 64];    // 32 KB
  __shared__ int gi[512];                               // 2 KB
  __shared__ float sL[2][256][2];                       // 4 KB
  int t = threadIdx.x;
  int L = blockIdx.x;
  int xcd = L & 7, jz = L >> 3;
  int bx = xcd * 64 + (jz >> 1);
  int jbase = (jz & 1) * 256;
  int ebase = bx * 128;
  int wid = t >> 6, lane = t & 63;
  int wr = wid >> 2, wc = wid & 3;
  int m = lane & 15, g = lane >> 4;

  gi[t] = gidx[(size_t)ebase * 4 + t];
  // prologue: As-direct chunks 0,1 via gload_lds (source-side swizzle)
#pragma unroll
  for (int s = 0; s < 2; ++s) {
#pragma unroll
    for (int q = 0; q < 2; ++q) {
      int slot = q * 512 + t;
      int r = slot >> 3, c16 = slot & 7;
      gload_lds16(XAb + (size_t)(ebase + r) * 128 + s * 64 + (c16 ^ (r & 7)) * 8,
                  &As[s][slot * 8]);
    }
  }
  VMCNT(0);
  __syncthreads();

  const int r0 = t >> 3, cc = t & 7;
  int iP13[2], iQ13[2], iP24[2], iQ24[2];
#pragma unroll
  for (int q2 = 0; q2 < 2; ++q2) {
    int r = r0 + q2 * 64;
    iP13[q2] = gi[r * 4 + 0]; iQ13[q2] = gi[r * 4 + 2];
    iP24[q2] = gi[r * 4 + 1]; iQ24[q2] = gi[r * 4 + 3];
  }
  // Wt fragment base pointers (loop-invariant)
  const uint16_t* wbase[4];
#pragma unroll
  for (int cf = 0; cf < 4; ++cf)
    wbase[cf] = Wt + (size_t)(jbase + wc * 64 + cf * 16 + m) * 640 + g * 8;

  uint4 grP[2], grQ[2];

  f32x4 acc[4][4];  // [edge-frag r][j-frag cf]
  f32x4 zero = {0.f, 0.f, 0.f, 0.f};
#pragma unroll
  for (int r = 0; r < 4; ++r)
#pragma unroll
    for (int c = 0; c < 4; ++c) acc[r][c] = zero;

#pragma unroll
  for (int u = 0; u < 10; ++u) {
    // --- retire gathers G(u+1), compute features, ds_write chunk u+1 ---
    if (u >= 1 && u <= 8) {
      VMCNT(0);
      SCHEDB;
      const int su = u + 1;
      const bool sum_op = (((su - 2) >> 1) & 1) == 0;
#pragma unroll
      for (int q2 = 0; q2 < 2; ++q2) {
        int r = r0 + q2 * 64;
        uint4 P = grP[q2], Q = grQ[q2];
        uint4 R;
        if (sum_op) {
          R.x = packbf(bflo(P.x) + bflo(Q.x), bfhi(P.x) + bfhi(Q.x));
          R.y = packbf(bflo(P.y) + bflo(Q.y), bfhi(P.y) + bfhi(Q.y));
          R.z = packbf(bflo(P.z) + bflo(Q.z), bfhi(P.z) + bfhi(Q.z));
          R.w = packbf(bflo(P.w) + bflo(Q.w), bfhi(P.w) + bfhi(Q.w));
        } else {
          R.x = packbf(fabsf(bflo(P.x) - bflo(Q.x)), fabsf(bfhi(P.x) - bfhi(Q.x)));
          R.y = packbf(fabsf(bflo(P.y) - bflo(Q.y)), fabsf(bfhi(P.y) - bfhi(Q.y)));
          R.z = packbf(fabsf(bflo(P.z) - bflo(Q.z)), fabsf(bfhi(P.z) - bfhi(Q.z)));
          R.w = packbf(fabsf(bflo(P.w) - bflo(Q.w)), fabsf(bfhi(P.w) - bfhi(Q.w)));
        }
        *(uint4*)&As[su & 1][(r * 8 + (cc ^ (r & 7))) * 8] = R;
      }
    }
    // --- issue Wt loads (kit0 then kit1), then gathers G(u+2) ---
    uint4 wt0[4], wt1[4];
#pragma unroll
    for (int cf = 0; cf < 4; ++cf) wt0[cf] = gload16(wbase[cf] + u * 64);
#pragma unroll
    for (int cf = 0; cf < 4; ++cf) wt1[cf] = gload16(wbase[cf] + u * 64 + 32);
    if (u <= 7) {
      const int v = u + 2;
      const int coffv = (v & 1) * 64;
      const int pr = (v - 2) >> 2;
#pragma unroll
      for (int q2 = 0; q2 < 2; ++q2) {
        int ip = pr ? iP24[q2] : iP13[q2];
        int iq = pr ? iQ24[q2] : iQ13[q2];
        grP[q2] = gload16(XAb + (size_t)ip * 128 + coffv + cc * 8);
        grQ[q2] = gload16(XAb + (size_t)iq * 128 + coffv + cc * 8);
      }
    }
    SCHEDB;
    // --- kit 0 ---
    {
      bf16x8 af[4];
#pragma unroll
      for (int r = 0; r < 4; ++r) {
        int row = wr * 64 + r * 16 + m;
        af[r] = *(const bf16x8*)&As[u & 1][row * 64 + ((0 * 4 + g) ^ (m & 7)) * 8];
      }
      if (u <= 7) { VMCNT(8); } else { VMCNT(4); }   // wt0 ready
      SCHEDB;
      union { uint4 u4; bf16x8 v; } w;
#pragma unroll
      for (int cf = 0; cf < 4; ++cf) {
        w.u4 = wt0[cf];
#pragma unroll
        for (int r = 0; r < 4; ++r)
          acc[r][cf] = __builtin_amdgcn_mfma_f32_16x16x32_bf16(w.v, af[r], acc[r][cf], 0, 0, 0);
      }
    }
    // --- kit 1 ---
    {
      bf16x8 af[4];
#pragma unroll
      for (int r = 0; r < 4; ++r) {
        int row = wr * 64 + r * 16 + m;
        af[r] = *(const bf16x8*)&As[u & 1][row * 64 + ((1 * 4 + g) ^ (m & 7)) * 8];
      }
      if (u <= 7) { VMCNT(4); } else { VMCNT(0); }   // wt1 ready, keep G(u+2)
      SCHEDB;
      union { uint4 u4; bf16x8 v; } w;
#pragma unroll
      for (int cf = 0; cf < 4; ++cf) {
        w.u4 = wt1[cf];
#pragma unroll
        for (int r = 0; r < 4; ++r)
          acc[r][cf] = __builtin_amdgcn_mfma_f32_16x16x32_bf16(w.v, af[r], acc[r][cf], 0, 0, 0);
      }
    }
    LGKM0;
    __builtin_amdgcn_s_barrier();
    SCHEDB;
  }

  // epilogue: D[j][edge]: lane&15 = edge, regs = 4 consecutive j (g*4+q)
  float s1[4][4], s2[4][4];
#pragma unroll
  for (int cf = 0; cf < 4; ++cf)
#pragma unroll
    for (int q = 0; q < 4; ++q) { s1[cf][q] = 0.f; s2[cf][q] = 0.f; }

#pragma unroll
  for (int cf = 0; cf < 4; ++cf) {
    f32x4 bv = *(const f32x4*)(biasF + jbase + wc * 64 + cf * 16 + g * 4);
#pragma unroll
    for (int r = 0; r < 4; ++r) {
      int eg = ebase + wr * 64 + r * 16 + m;
      float v0 = acc[r][cf][0] + bv[0];
      float v1 = acc[r][cf][1] + bv[1];
      float v2 = acc[r][cf][2] + bv[2];
      float v3 = acc[r][cf][3] + bv[3];
      s1[cf][0] += v0; s2[cf][0] += v0 * v0;
      s1[cf][1] += v1; s2[cf][1] += v1 * v1;
      s1[cf][2] += v2; s2[cf][2] += v2 * v2;
      s1[cf][3] += v3; s2[cf][3] += v3 * v3;
      uint2 o;
      o.x = packbf(v0, v1);
      o.y = packbf(v2, v3);
      *(uint2*)(Y + (size_t)eg * 512 + jbase + wc * 64 + cf * 16 + g * 4) = o;
    }
  }
#pragma unroll
  for (int cf = 0; cf < 4; ++cf)
#pragma unroll
    for (int q = 0; q < 4; ++q) {
#pragma unroll
      for (int off = 1; off < 16; off <<= 1) {
        s1[cf][q] += __shfl_xor(s1[cf][q], off);
        s2[cf][q] += __shfl_xor(s2[cf][q], off);
      }
    }
  if (m == 0) {
#pragma unroll
    for (int cf = 0; cf < 4; ++cf)
#pragma unroll
      for (int q = 0; q < 4; ++q) {
        int jl = wc * 64 + cf * 16 + g * 4 + q;
        sL[wr][jl][0] = s1[cf][q];
        sL[wr][jl][1] = s2[cf][q];
      }
  }
  __syncthreads();
  if (t < 256) {
    float a1 = sL[0][t][0] + sL[1][t][0];
    float a2 = sL[0][t][1] + sL[1][t][1];
    float* p = part + ((size_t)bx * 512 + jbase + t) * 2;
    p[0] = a1; p[1] = a2;
  }
}

// ---------------- K3b2: finalize per-column mean/rsqrt (512 partials) ----------
__global__ void k3b2(const float* __restrict__ part, float* __restrict__ statF) {
  int col = blockIdx.x, t = threadIdx.x;
  float s1 = 0, s2 = 0;
  for (int k = t; k < 512; k += 128) {
    const float* p = part + ((size_t)k * 512 + col) * 2;
    s1 += p[0]; s2 += p[1];
  }
  for (int off = 32; off; off >>= 1) { s1 += __shfl_down(s1, off); s2 += __shfl_down(s2, off); }
  __shared__ float sh[4];
  if ((t & 63) == 0) { sh[(t >> 6) * 2] = s1; sh[(t >> 6) * 2 + 1] = s2; }
  __syncthreads();
  if (t == 0) {
    s1 = sh[0] + sh[2]; s2 = sh[1] + sh[3];
    float mean = s1 * (1.0f / 65536.0f);
    float var = s2 * (1.0f / 65536.0f) - mean * mean;
    statF[col * 2] = mean;
    statF[col * 2 + 1] = rsqrtf(var + 1e-5f);
  }
}

// ---------------- K4: gate + blend, channel-major out (R10, unchanged) ----------
__global__ __launch_bounds__(256) void k4_final(
    const uint16_t* __restrict__ Y, const float* __restrict__ statF,
    const float* __restrict__ x0b, const float* __restrict__ x1b,
    float* __restrict__ outb) {
  __shared__ float W0[128][65];
  __shared__ float mA[128], rA[128], mB[128], rB[128];
  int t = threadIdx.x;
  int L = blockIdx.x;
  int xcd = L & 7, jz = L >> 3;
  int n0 = (xcd * 128 + (jz >> 1)) * 64;
  int ch = jz & 1;
  if (t < 128) {
    mA[t] = statF[(ch * 128 + t) * 2];
    rA[t] = statF[(ch * 128 + t) * 2 + 1];
  } else {
    int q = t - 128;
    mB[q] = statF[(256 + ch * 128 + q) * 2];
    rB[q] = statF[(256 + ch * 128 + q) * 2 + 1];
  }
  __syncthreads();
  const char* Ybase = (const char*)Y;
  for (int i = t; i < 64 * 64; i += 256) {
    int row = i >> 6, cp = i & 63;
    const char* yr = Ybase + (size_t)(n0 + row) * 1024;
    uint32_t ya2 = *(const uint32_t*)(yr + ch * 256 + cp * 4);
    uint32_t yb2 = *(const uint32_t*)(yr + 512 + ch * 256 + cp * 4);
    int c0 = 2 * cp, c1 = 2 * cp + 1;
    float wa0 = sigm((bflo(ya2) - mA[c0]) * rA[c0]);
    float wa1 = sigm((bfhi(ya2) - mA[c1]) * rA[c1]);
    float wb0 = sigm((bflo(yb2) - mB[c0]) * rB[c0]);
    float wb1 = sigm((bfhi(yb2) - mB[c1]) * rB[c1]);
    W0[c0][row] = sigm(wa0 - wb0);
    W0[c1][row] = sigm(wa1 - wb1);
  }
  __syncthreads();
  int nn = t & 63, cg = t >> 6;
  for (int cc2 = cg; cc2 < 128; cc2 += 4) {
    int c = ch * 128 + cc2;
    size_t gidx2 = (size_t)c * NEDGE + n0 + nn;
    float w0 = W0[cc2][nn];
    outb[gidx2] = x0b[gidx2] * w0 + x1b[gidx2] * (1.0f - w0);
  }
}

extern "C" void kernel_launch(void* const* d_in, const int* in_sizes, int n_in,
                              void* d_out, int out_size, void* d_ws, size_t ws_size,
                              hipStream_t stream) {
  const float* x0 = (const float*)d_in[0];
  const float* x1 = (const float*)d_in[1];
  const int* gemm = (const int*)d_in[2];
  const float* Wa = (const float*)d_in[3];
  const float* ba = (const float*)d_in[4];
  const float* Wb = (const float*)d_in[5];
  const float* bb = (const float*)d_in[6];
  const float* Wal = (const float*)d_in[7];
  const float* bal = (const float*)d_in[8];
  const float* Wbl = (const float*)d_in[9];
  const float* bbl = (const float*)d_in[10];
  const float* Wat = (const float*)d_in[11];
  const float* bat = (const float*)d_in[12];
  const float* Wbt = (const float*)d_in[13];
  const float* bbt = (const float*)d_in[14];
  const float* Waf = (const float*)d_in[15];
  const float* baf = (const float*)d_in[16];
  const float* Wbf = (const float*)d_in[17];
  const float* bbf = (const float*)d_in[18];
  float* out = (float*)d_out;

  char* ws = (char*)d_ws;
  uint16_t* XA   = (uint16_t*)ws;                    // 33,554,432 B
  uint16_t* Yb   = (uint16_t*)(ws + 33554432);       // 67,108,864 B (per-batch reuse)
  uint16_t* Wt   = (uint16_t*)(ws + 100663296);      // 655,360 B
  uint16_t* W1bf = (uint16_t*)(ws + 101318656);      // 65,536 B
  float*    biasF= (float*)(ws + 101384192);         // 2,048 B
  float*    part = (float*)(ws + 101386240);         // 2,097,152 B (per-batch reuse)
  float*    statF= (float*)(ws + 103483392);         // 8,192 B

  k_compose<<<dim3(1280), dim3(256), 0, stream>>>(Wal, Wbl, Wat, Wbt, Waf, Wbf, Wt);
  k_bias<<<dim3(2), dim3(256), 0, stream>>>(bal, bat, baf, bbl, bbt, bbf, Waf, Wbf, biasF);
  k_wt1<<<dim3(128), dim3(256), 0, stream>>>(Wa, Wb, W1bf);
  k1_xa<<<dim3(2048), dim3(256), 0, stream>>>(x0, x1, W1bf, ba, bb, XA);

  for (int b = 0; b < 2; ++b) {
    const uint16_t* XAb = XA + (size_t)b * NEDGE * 128;
    k23_gemm<<<dim3(1024), dim3(512), 0, stream>>>(
        XAb, gemm + (size_t)b * NEDGE * 4, Wt, biasF, Yb, part);
    k3b2<<<dim3(512), dim3(128), 0, stream>>>(part, statF + b * 1024);
    k4_final<<<dim3(2048), dim3(256), 0, stream>>>(
        Yb, statF + b * 1024, x0 + (size_t)b * 256 * NEDGE,
        x1 + (size_t)b * 256 * NEDGE, out + (size_t)b * 256 * NEDGE);
  }
}

// Round 13
// 413.633 us; speedup vs baseline: 1.3847x; 1.2121x over previous
//
#include <hip/hip_runtime.h>
#include <stdint.h>

// Problem constants: B=2, C=256, N=65536
#define NEDGE 65536

typedef __attribute__((ext_vector_type(4))) float f32x4;
typedef __attribute__((ext_vector_type(8))) __bf16 bf16x8;

#define VMCNT(n) asm volatile("s_waitcnt vmcnt(" #n ")" ::: "memory")
#define VMCNT_LGKM0(n) asm volatile("s_waitcnt vmcnt(" #n ") lgkmcnt(0)" ::: "memory")
#define LGKM0 asm volatile("s_waitcnt lgkmcnt(0)" ::: "memory")
#define SCHEDB __builtin_amdgcn_sched_barrier(0)

__device__ __forceinline__ uint16_t f2bf(float f) {
  union { float f; uint32_t u; } v; v.f = f;
  uint32_t r = v.u + 0x7FFFu + ((v.u >> 16) & 1u);
  return (uint16_t)(r >> 16);
}
__device__ __forceinline__ float bflo(uint32_t u) {
  union { uint32_t u; float f; } v; v.u = u << 16; return v.f;
}
__device__ __forceinline__ float bfhi(uint32_t u) {
  union { uint32_t u; float f; } v; v.u = u & 0xFFFF0000u; return v.f;
}
__device__ __forceinline__ uint32_t packbf(float lo, float hi) {
  return (uint32_t)f2bf(lo) | ((uint32_t)f2bf(hi) << 16);
}
__device__ __forceinline__ void gload_lds16(const void* g, void* l) {
  __builtin_amdgcn_global_load_lds(
      (__attribute__((address_space(1))) uint32_t*)(uintptr_t)g,
      (__attribute__((address_space(3))) uint32_t*)l, 16, 0, 0);
}
__device__ __forceinline__ float sigm(float z) { return 1.0f / (1.0f + __expf(-z)); }

// ---------------- K0: weight composition ----------------
__global__ void k_compose(const float* __restrict__ Wal, const float* __restrict__ Wbl,
                          const float* __restrict__ Wat, const float* __restrict__ Wbt,
                          const float* __restrict__ Waf, const float* __restrict__ Wbf,
                          uint16_t* __restrict__ Wt) {
  int id = blockIdx.x * 256 + threadIdx.x;
  if (id >= 512 * 640) return;
  int j = id / 640, kk = id % 640;
  const float* Wf = (j < 256) ? Waf : Wbf;
  const float* Wl = (j < 256) ? Wal : Wbl;
  const float* Wr = (j < 256) ? Wat : Wbt;
  int jj = j & 255;
  float acc = 0.f;
  if (kk < 128) {
    int c = kk;
    for (int o = 0; o < 128; ++o) acc += Wl[o * 128 + c] * Wf[jj * 256 + o];
    for (int o = 0; o < 128; ++o) acc += Wr[(o * 128 + c) * 5 + 0] * Wf[jj * 256 + 128 + o];
  } else {
    int blkid = (kk - 128) >> 7;
    int gk = (blkid == 0) ? 1 : (blkid == 1) ? 3 : (blkid == 2) ? 2 : 4;
    int c = (kk - 128) & 127;
    for (int o = 0; o < 128; ++o) acc += Wr[(o * 128 + c) * 5 + gk] * Wf[jj * 256 + 128 + o];
  }
  Wt[j * 640 + kk] = f2bf(acc);
}

__global__ void k_bias(const float* __restrict__ bal, const float* __restrict__ bat,
                       const float* __restrict__ baf, const float* __restrict__ bbl,
                       const float* __restrict__ bbt, const float* __restrict__ bbf,
                       const float* __restrict__ Waf, const float* __restrict__ Wbf,
                       float* __restrict__ biasF) {
  int id = blockIdx.x * 256 + threadIdx.x;
  if (id >= 512) return;
  const float* Wf = (id < 256) ? Waf : Wbf;
  const float* bl = (id < 256) ? bal : bbl;
  const float* bt = (id < 256) ? bat : bbt;
  const float* bsf = (id < 256) ? baf : bbf;
  int jj = id & 255;
  float acc = bsf[jj];
  for (int o = 0; o < 128; ++o) acc += Wf[jj * 256 + o] * bl[o];
  for (int o = 0; o < 128; ++o) acc += Wf[jj * 256 + 128 + o] * bt[o];
  biasF[id] = acc;
}

// First-layer weights -> bf16, [side][j][c] row-major
__global__ void k_wt1(const float* __restrict__ Wa, const float* __restrict__ Wb,
                      uint16_t* __restrict__ W1bf) {
  int id = blockIdx.x * 256 + threadIdx.x;
  if (id >= 2 * 64 * 256) return;
  int side = id >> 14, r = id & 16383;
  W1bf[id] = f2bf(side ? Wb[r] : Wa[r]);
}

// ---------------- K1 (R7-exact): XA = [Wa@x0+ba | Wb@x1+bb] ----------------
// Swapped-operand MFMA, gload_lds staging, counted vmcnt + raw barriers.
__global__ __launch_bounds__(256) void k1_xa(
    const float* __restrict__ x0, const float* __restrict__ x1,
    const uint16_t* __restrict__ W1bf, const float* __restrict__ ba,
    const float* __restrict__ bb, uint16_t* __restrict__ XA) {
  __shared__ __align__(16) float Xs[3][32 * 128];    // 3 x 16 KB
  __shared__ __align__(16) uint16_t Bs[64 * 256];    // 32 KB
  int t = threadIdx.x;
  int side = blockIdx.y, b = blockIdx.z;
  int n0 = blockIdx.x * 128;
  const float* xin = (side ? x1 : x0) + (size_t)b * 256 * NEDGE + n0;
  const uint16_t* wsrc = W1bf + side * 64 * 256;

#pragma unroll
  for (int q = 0; q < 8; ++q) {
    int s = q * 256 + t;
    int j = s >> 5, pb = s & 31;
    int lb = pb ^ (j & 7);
    gload_lds16(wsrc + j * 256 + lb * 8, &Bs[s * 8]);
  }
#pragma unroll
  for (int c = 0; c < 2; ++c) {
#pragma unroll
    for (int q = 0; q < 4; ++q) {
      int s = q * 256 + t;
      int cl = s >> 5, pb = s & 31;
      int lb = pb ^ (((cl >> 3) & 3) << 2);
      gload_lds16(xin + (size_t)(c * 32 + cl) * NEDGE + lb * 4, &Xs[c][s * 4]);
    }
  }

  int wv = t >> 6, l = t & 63;
  int m = l & 15, g = l >> 4;
  int pcol[2];
#pragma unroll
  for (int nf = 0; nf < 2; ++nf) {
    int n = wv * 32 + nf * 16 + m;
    pcol[nf] = (((n >> 2) ^ (g << 2)) << 2) + (n & 3);
  }

  f32x4 acc[2][4];
  f32x4 zero = {0.f, 0.f, 0.f, 0.f};
#pragma unroll
  for (int nf = 0; nf < 2; ++nf)
#pragma unroll
    for (int jf = 0; jf < 4; ++jf) acc[nf][jf] = zero;

#pragma unroll
  for (int ks = 0; ks < 8; ++ks) {
    if (ks < 6) {
      const float* xc = xin + (size_t)(ks + 2) * 32 * NEDGE;
#pragma unroll
      for (int q = 0; q < 4; ++q) {
        int s = q * 256 + t;
        int cl = s >> 5, pb = s & 31;
        int lb = pb ^ (((cl >> 3) & 3) << 2);
        gload_lds16(xc + (size_t)cl * NEDGE + lb * 4, &Xs[(ks + 2) % 3][s * 4]);
      }
      VMCNT(8);
    } else if (ks == 6) {
      VMCNT(4);
    } else {
      VMCNT(0);
    }
    SCHEDB;
    __builtin_amdgcn_s_barrier();
    SCHEDB;

    const float* Xb = Xs[ks % 3];
    bf16x8 af[4];
#pragma unroll
    for (int jf = 0; jf < 4; ++jf) {
      int jloc = jf * 16 + m;
      int pbb = (ks * 4 + g) ^ (jloc & 7);
      af[jf] = *(const bf16x8*)&Bs[jloc * 256 + pbb * 8];
    }
#pragma unroll
    for (int nf = 0; nf < 2; ++nf) {
      const float* base = Xb + g * 8 * 128 + pcol[nf];
      float xv[8];
#pragma unroll
      for (int i = 0; i < 8; ++i) xv[i] = base[i * 128];
      union { bf16x8 v; uint32_t u[4]; } bx;
      bx.u[0] = packbf(xv[0], xv[1]);
      bx.u[1] = packbf(xv[2], xv[3]);
      bx.u[2] = packbf(xv[4], xv[5]);
      bx.u[3] = packbf(xv[6], xv[7]);
#pragma unroll
      for (int jf = 0; jf < 4; ++jf)
        acc[nf][jf] = __builtin_amdgcn_mfma_f32_16x16x32_bf16(af[jf], bx.v, acc[nf][jf], 0, 0, 0);
    }
    LGKM0;
    __builtin_amdgcn_s_barrier();
    SCHEDB;
  }

  const float* bias = side ? bb : ba;
  uint16_t* XAb = XA + (size_t)b * NEDGE * 128;
#pragma unroll
  for (int jf = 0; jf < 4; ++jf) {
    f32x4 bv = *(const f32x4*)(bias + jf * 16 + g * 4);
#pragma unroll
    for (int nf = 0; nf < 2; ++nf) {
      int n = n0 + wv * 32 + nf * 16 + m;
      uint2 o;
      o.x = packbf(acc[nf][jf][0] + bv[0], acc[nf][jf][1] + bv[1]);
      o.y = packbf(acc[nf][jf][2] + bv[2], acc[nf][jf][3] + bv[3]);
      *(uint2*)(XAb + (size_t)n * 128 + side * 64 + jf * 16 + g * 4) = o;
    }
  }
}

// ---------------- K23 (R7-exact body + XCD-bijective swizzle) ----------------
// Fused gather+features+GEMM+stats. As dbuf + Bs2 dbuf (104KB, 1 blk/CU).
// Counted vmcnt, raw barriers, everything issued >=1 step ahead (R7 ledger).
__global__ __launch_bounds__(512) void k23_gemm(
    const uint16_t* __restrict__ XAb, const int* __restrict__ gidx,
    const uint16_t* __restrict__ Wt, const float* __restrict__ biasF,
    uint16_t* __restrict__ Y, float* __restrict__ part) {
  __shared__ __align__(16) uint16_t As[2][128 * 64];    // 32 KB
  __shared__ __align__(16) uint16_t Bs2[2][256 * 64];   // 64 KB
  __shared__ int gi[512];                               // 2 KB
  __shared__ float sL[2][256][2];                       // 4 KB
  int t = threadIdx.x;
  // XCD-bijective decode (R10-validated: FETCH 74->47 MB at equal time):
  // XCD k owns 64 consecutive row-tiles; both col-tiles adjacent on one XCD.
  int L = blockIdx.x;
  int xcd = L & 7, jz = L >> 3;
  int bx = xcd * 64 + (jz >> 1);
  int jbase = (jz & 1) * 256;
  int ebase = bx * 128;
  int wid = t >> 6, lane = t & 63;
  int wr = wid >> 2, wc = wid & 3;
  int m = lane & 15, g = lane >> 4;

  gi[t] = gidx[(size_t)ebase * 4 + t];
  __syncthreads();

  const int r0 = t >> 3, cc = t & 7;
  int iP13[2], iQ13[2], iP24[2], iQ24[2];
#pragma unroll
  for (int q2 = 0; q2 < 2; ++q2) {
    int r = r0 + q2 * 64;
    iP13[q2] = gi[r * 4 + 0]; iQ13[q2] = gi[r * 4 + 2];
    iP24[q2] = gi[r * 4 + 1]; iQ24[q2] = gi[r * 4 + 3];
  }

  uint4 grP[2][2], grQ[2][2];  // [chunk parity][slot]

#define ISSUE_GATH(v)                                                           \
  do {                                                                          \
    const int coffv = ((v) & 1) * 64;                                           \
    const int pr = ((v) - 2) >> 2; /* 0: nbrs(0,2), 1: nbrs(1,3) */             \
    _Pragma("unroll")                                                           \
    for (int q2 = 0; q2 < 2; ++q2) {                                            \
      int ip = pr ? iP24[q2] : iP13[q2];                                        \
      int iq = pr ? iQ24[q2] : iQ13[q2];                                        \
      grP[(v) & 1][q2] = *(const uint4*)(XAb + (size_t)ip * 128 + coffv + cc * 8); \
      grQ[(v) & 1][q2] = *(const uint4*)(XAb + (size_t)iq * 128 + coffv + cc * 8); \
    }                                                                           \
  } while (0)

#define ISSUE_BS(s_)                                                            \
  do {                                                                          \
    _Pragma("unroll")                                                           \
    for (int q = 0; q < 4; ++q) {                                               \
      int slot = q * 512 + t; int r = slot >> 3, c16 = slot & 7;                \
      gload_lds16(Wt + (size_t)(jbase + r) * 640 + (s_) * 64 + (c16 ^ (r & 7)) * 8, \
                  &Bs2[(s_) & 1][slot * 8]);                                    \
    }                                                                           \
  } while (0)

#define ISSUE_AS_DIRECT(s_)                                                     \
  do {                                                                          \
    _Pragma("unroll")                                                           \
    for (int q = 0; q < 2; ++q) {                                               \
      int slot = q * 512 + t; int r = slot >> 3, c16 = slot & 7;                \
      gload_lds16(XAb + (size_t)(ebase + r) * 128 + (s_) * 64 + (c16 ^ (r & 7)) * 8, \
                  &As[(s_) & 1][slot * 8]);                                     \
    }                                                                           \
  } while (0)

  // prologue: gath(2) first (oldest), then As0,Bs0,As1,Bs1
  ISSUE_GATH(2);
  ISSUE_AS_DIRECT(0);
  ISSUE_BS(0);
  ISSUE_AS_DIRECT(1);
  ISSUE_BS(1);

  f32x4 acc[4][4];  // [edge-frag r][j-frag cf]
  f32x4 zero = {0.f, 0.f, 0.f, 0.f};
#pragma unroll
  for (int r = 0; r < 4; ++r)
#pragma unroll
    for (int c = 0; c < 4; ++c) acc[r][c] = zero;

#pragma unroll
  for (int u = 0; u < 10; ++u) {
    const int su = u + 1;  // chunk being ds_written this iter
    if (su >= 2 && su <= 9) {
      if (u == 1) { VMCNT(6); } else { VMCNT(4); }  // gather regs for su ready
      const int sum_op = (((su - 2) >> 1) & 1) == 0;
      const int bi = su & 1;
#pragma unroll
      for (int q2 = 0; q2 < 2; ++q2) {
        int r = r0 + q2 * 64;
        uint4 P = grP[bi][q2], Q = grQ[bi][q2];
        uint4 R;
        if (sum_op) {
          R.x = packbf(bflo(P.x) + bflo(Q.x), bfhi(P.x) + bfhi(Q.x));
          R.y = packbf(bflo(P.y) + bflo(Q.y), bfhi(P.y) + bfhi(Q.y));
          R.z = packbf(bflo(P.z) + bflo(Q.z), bfhi(P.z) + bfhi(Q.z));
          R.w = packbf(bflo(P.w) + bflo(Q.w), bfhi(P.w) + bfhi(Q.w));
        } else {
          R.x = packbf(fabsf(bflo(P.x) - bflo(Q.x)), fabsf(bfhi(P.x) - bfhi(Q.x)));
          R.y = packbf(fabsf(bflo(P.y) - bflo(Q.y)), fabsf(bfhi(P.y) - bfhi(Q.y)));
          R.z = packbf(fabsf(bflo(P.z) - bflo(Q.z)), fabsf(bfhi(P.z) - bfhi(Q.z)));
          R.w = packbf(fabsf(bflo(P.w) - bflo(Q.w)), fabsf(bfhi(P.w) - bfhi(Q.w)));
        }
        *(uint4*)&As[bi][(r * 8 + (cc ^ (r & 7))) * 8] = R;
      }
    }
    if (u + 2 >= 3 && u + 2 <= 9) ISSUE_GATH(u + 2);
    if (su >= 2 && su <= 9) ISSUE_BS(su);
    // main wait: chunk u's Bs (+As direct) landed; keep newest 8 in flight
    if (u == 0) { VMCNT_LGKM0(6); }
    else if (u <= 7) { VMCNT_LGKM0(8); }
    else if (u == 8) { VMCNT_LGKM0(4); }
    else { VMCNT_LGKM0(0); }
    SCHEDB;
    __builtin_amdgcn_s_barrier();
    SCHEDB;

    const uint16_t* Ab = As[u & 1];
    const uint16_t* Bb = Bs2[u & 1];
#pragma unroll
    for (int kit = 0; kit < 2; ++kit) {
      bf16x8 af[4], bf[4];
#pragma unroll
      for (int r = 0; r < 4; ++r) {
        int row = wr * 64 + r * 16 + m;
        af[r] = *(const bf16x8*)&Ab[row * 64 + ((kit * 4 + g) ^ (m & 7)) * 8];
      }
#pragma unroll
      for (int cf = 0; cf < 4; ++cf) {
        int row = wc * 64 + cf * 16 + m;
        bf[cf] = *(const bf16x8*)&Bb[row * 64 + ((kit * 4 + g) ^ (m & 7)) * 8];
      }
      // swapped: A=Wt (M=j), B=edges (N=edge) -> D[j][edge]
#pragma unroll
      for (int r = 0; r < 4; ++r)
#pragma unroll
        for (int cf = 0; cf < 4; ++cf)
          acc[r][cf] = __builtin_amdgcn_mfma_f32_16x16x32_bf16(bf[cf], af[r], acc[r][cf], 0, 0, 0);
    }
    __builtin_amdgcn_s_barrier();
    SCHEDB;
  }
#undef ISSUE_GATH
#undef ISSUE_BS
#undef ISSUE_AS_DIRECT

  // epilogue: D[j][edge]: lane&15 = edge, regs = 4 consecutive j (g*4+q)
  float s1[4][4], s2[4][4];  // [cf][q]
#pragma unroll
  for (int cf = 0; cf < 4; ++cf)
#pragma unroll
    for (int q = 0; q < 4; ++q) { s1[cf][q] = 0.f; s2[cf][q] = 0.f; }

#pragma unroll
  for (int cf = 0; cf < 4; ++cf) {
    f32x4 bv = *(const f32x4*)(biasF + jbase + wc * 64 + cf * 16 + g * 4);
#pragma unroll
    for (int r = 0; r < 4; ++r) {
      int eg = ebase + wr * 64 + r * 16 + m;
      float v0 = acc[r][cf][0] + bv[0];
      float v1 = acc[r][cf][1] + bv[1];
      float v2 = acc[r][cf][2] + bv[2];
      float v3 = acc[r][cf][3] + bv[3];
      s1[cf][0] += v0; s2[cf][0] += v0 * v0;
      s1[cf][1] += v1; s2[cf][1] += v1 * v1;
      s1[cf][2] += v2; s2[cf][2] += v2 * v2;
      s1[cf][3] += v3; s2[cf][3] += v3 * v3;
      uint2 o;
      o.x = packbf(v0, v1);
      o.y = packbf(v2, v3);
      *(uint2*)(Y + (size_t)eg * 512 + jbase + wc * 64 + cf * 16 + g * 4) = o;
    }
  }
#pragma unroll
  for (int cf = 0; cf < 4; ++cf)
#pragma unroll
    for (int q = 0; q < 4; ++q) {
#pragma unroll
      for (int off = 1; off < 16; off <<= 1) {
        s1[cf][q] += __shfl_xor(s1[cf][q], off);
        s2[cf][q] += __shfl_xor(s2[cf][q], off);
      }
    }
  if (m == 0) {
#pragma unroll
    for (int cf = 0; cf < 4; ++cf)
#pragma unroll
      for (int q = 0; q < 4; ++q) {
        int jl = wc * 64 + cf * 16 + g * 4 + q;
        sL[wr][jl][0] = s1[cf][q];
        sL[wr][jl][1] = s2[cf][q];
      }
  }
  __syncthreads();
  if (t < 256) {
    float a1 = sL[0][t][0] + sL[1][t][0];
    float a2 = sL[0][t][1] + sL[1][t][1];
    float* p = part + ((size_t)bx * 512 + jbase + t) * 2;
    p[0] = a1; p[1] = a2;
  }
}

// ---------------- K3b2: finalize per-column mean/rsqrt ----------------
__global__ void k3b2(const float* __restrict__ part, float* __restrict__ statF) {
  int col = blockIdx.x, t = threadIdx.x;
  float s1 = 0, s2 = 0;
  for (int k = t; k < 512; k += 128) {
    const float* p = part + ((size_t)k * 512 + col) * 2;
    s1 += p[0]; s2 += p[1];
  }
  for (int off = 32; off; off >>= 1) { s1 += __shfl_down(s1, off); s2 += __shfl_down(s2, off); }
  __shared__ float sh[4];
  if ((t & 63) == 0) { sh[(t >> 6) * 2] = s1; sh[(t >> 6) * 2 + 1] = s2; }
  __syncthreads();
  if (t == 0) {
    s1 = sh[0] + sh[2]; s2 = sh[1] + sh[3];
    float mean = s1 * (1.0f / 65536.0f);
    float var = s2 * (1.0f / 65536.0f) - mean * mean;
    statF[col * 2] = mean;
    statF[col * 2 + 1] = rsqrtf(var + 1e-5f);
  }
}

// ---------------- K4 (R7-exact): gate + blend, channel-major out ----------------
__global__ __launch_bounds__(256) void k4_final(
    const uint16_t* __restrict__ Y, const float* __restrict__ statF,
    const float* __restrict__ x0b, const float* __restrict__ x1b,
    float* __restrict__ outb) {
  __shared__ float W0[128][65];
  __shared__ float mA[128], rA[128], mB[128], rB[128];
  int t = threadIdx.x;
  int n0 = blockIdx.x * 64;
  int ch = blockIdx.y;
  if (t < 128) {
    mA[t] = statF[(ch * 128 + t) * 2];
    rA[t] = statF[(ch * 128 + t) * 2 + 1];
  } else {
    int q = t - 128;
    mB[q] = statF[(256 + ch * 128 + q) * 2];
    rB[q] = statF[(256 + ch * 128 + q) * 2 + 1];
  }
  __syncthreads();
  const char* Ybase = (const char*)Y;
  for (int i = t; i < 64 * 64; i += 256) {
    int row = i >> 6, cp = i & 63;
    const char* yr = Ybase + (size_t)(n0 + row) * 1024;
    uint32_t ya2 = *(const uint32_t*)(yr + ch * 256 + cp * 4);
    uint32_t yb2 = *(const uint32_t*)(yr + 512 + ch * 256 + cp * 4);
    int c0 = 2 * cp, c1 = 2 * cp + 1;
    float wa0 = sigm((bflo(ya2) - mA[c0]) * rA[c0]);
    float wa1 = sigm((bfhi(ya2) - mA[c1]) * rA[c1]);
    float wb0 = sigm((bflo(yb2) - mB[c0]) * rB[c0]);
    float wb1 = sigm((bfhi(yb2) - mB[c1]) * rB[c1]);
    W0[c0][row] = sigm(wa0 - wb0);
    W0[c1][row] = sigm(wa1 - wb1);
  }
  __syncthreads();
  int nn = t & 63, cg = t >> 6;
  for (int cc2 = cg; cc2 < 128; cc2 += 4) {
    int c = ch * 128 + cc2;
    size_t gidx2 = (size_t)c * NEDGE + n0 + nn;
    float w0 = W0[cc2][nn];
    outb[gidx2] = x0b[gidx2] * w0 + x1b[gidx2] * (1.0f - w0);
  }
}

extern "C" void kernel_launch(void* const* d_in, const int* in_sizes, int n_in,
                              void* d_out, int out_size, void* d_ws, size_t ws_size,
                              hipStream_t stream) {
  const float* x0 = (const float*)d_in[0];
  const float* x1 = (const float*)d_in[1];
  const int* gemm = (const int*)d_in[2];
  const float* Wa = (const float*)d_in[3];
  const float* ba = (const float*)d_in[4];
  const float* Wb = (const float*)d_in[5];
  const float* bb = (const float*)d_in[6];
  const float* Wal = (const float*)d_in[7];
  const float* bal = (const float*)d_in[8];
  const float* Wbl = (const float*)d_in[9];
  const float* bbl = (const float*)d_in[10];
  const float* Wat = (const float*)d_in[11];
  const float* bat = (const float*)d_in[12];
  const float* Wbt = (const float*)d_in[13];
  const float* bbt = (const float*)d_in[14];
  const float* Waf = (const float*)d_in[15];
  const float* baf = (const float*)d_in[16];
  const float* Wbf = (const float*)d_in[17];
  const float* bbf = (const float*)d_in[18];
  float* out = (float*)d_out;

  char* ws = (char*)d_ws;
  uint16_t* XA   = (uint16_t*)ws;                    // 33,554,432 B
  uint16_t* Yb   = (uint16_t*)(ws + 33554432);       // 67,108,864 B (per-batch reuse)
  uint16_t* Wt   = (uint16_t*)(ws + 100663296);      // 655,360 B
  uint16_t* W1bf = (uint16_t*)(ws + 101318656);      // 65,536 B
  float*    biasF= (float*)(ws + 101384192);         // 2,048 B
  float*    part = (float*)(ws + 101386240);         // 2,097,152 B (per-batch reuse)
  float*    statF= (float*)(ws + 103483392);         // 8,192 B

  k_compose<<<dim3(1280), dim3(256), 0, stream>>>(Wal, Wbl, Wat, Wbt, Waf, Wbf, Wt);
  k_bias<<<dim3(2), dim3(256), 0, stream>>>(bal, bat, baf, bbl, bbt, bbf, Waf, Wbf, biasF);
  k_wt1<<<dim3(128), dim3(256), 0, stream>>>(Wa, Wb, W1bf);
  k1_xa<<<dim3(512, 2, 2), dim3(256), 0, stream>>>(x0, x1, W1bf, ba, bb, XA);

  for (int b = 0; b < 2; ++b) {
    const uint16_t* XAb = XA + (size_t)b * NEDGE * 128;
    k23_gemm<<<dim3(1024), dim3(512), 0, stream>>>(
        XAb, gemm + (size_t)b * NEDGE * 4, Wt, biasF, Yb, part);
    k3b2<<<dim3(512), dim3(128), 0, stream>>>(part, statF + b * 1024);
    k4_final<<<dim3(1024, 2), dim3(256), 0, stream>>>(
        Yb, statF + b * 1024, x0 + (size_t)b * 256 * NEDGE,
        x1 + (size_t)b * 256 * NEDGE, out + (size_t)b * 256 * NEDGE);
  }
}

// Round 14
// 392.333 us; speedup vs baseline: 1.4599x; 1.0543x over previous
//
#include <hip/hip_runtime.h>
#include <stdint.h>

// Problem constants: B=2, C=256, N=65536
#define NEDGE 65536

typedef __attribute__((ext_vector_type(4))) float f32x4;
typedef __attribute__((ext_vector_type(8))) __bf16 bf16x8;

#define VMCNT(n) asm volatile("s_waitcnt vmcnt(" #n ")" ::: "memory")
#define VMCNT_LGKM0(n) asm volatile("s_waitcnt vmcnt(" #n ") lgkmcnt(0)" ::: "memory")
#define LGKM0 asm volatile("s_waitcnt lgkmcnt(0)" ::: "memory")
#define SCHEDB __builtin_amdgcn_sched_barrier(0)

__device__ __forceinline__ uint16_t f2bf(float f) {
  union { float f; uint32_t u; } v; v.f = f;
  uint32_t r = v.u + 0x7FFFu + ((v.u >> 16) & 1u);
  return (uint16_t)(r >> 16);
}
__device__ __forceinline__ float bflo(uint32_t u) {
  union { uint32_t u; float f; } v; v.u = u << 16; return v.f;
}
__device__ __forceinline__ float bfhi(uint32_t u) {
  union { uint32_t u; float f; } v; v.u = u & 0xFFFF0000u; return v.f;
}
__device__ __forceinline__ uint32_t packbf(float lo, float hi) {
  return (uint32_t)f2bf(lo) | ((uint32_t)f2bf(hi) << 16);
}
__device__ __forceinline__ void gload_lds16(const void* g, void* l) {
  __builtin_amdgcn_global_load_lds(
      (__attribute__((address_space(1))) uint32_t*)(uintptr_t)g,
      (__attribute__((address_space(3))) uint32_t*)l, 16, 0, 0);
}
__device__ __forceinline__ float sigm(float z) { return 1.0f / (1.0f + __expf(-z)); }

// ---------------- K0: weight composition ----------------
__global__ void k_compose(const float* __restrict__ Wal, const float* __restrict__ Wbl,
                          const float* __restrict__ Wat, const float* __restrict__ Wbt,
                          const float* __restrict__ Waf, const float* __restrict__ Wbf,
                          uint16_t* __restrict__ Wt) {
  int id = blockIdx.x * 256 + threadIdx.x;
  if (id >= 512 * 640) return;
  int j = id / 640, kk = id % 640;
  const float* Wf = (j < 256) ? Waf : Wbf;
  const float* Wl = (j < 256) ? Wal : Wbl;
  const float* Wr = (j < 256) ? Wat : Wbt;
  int jj = j & 255;
  float acc = 0.f;
  if (kk < 128) {
    int c = kk;
    for (int o = 0; o < 128; ++o) acc += Wl[o * 128 + c] * Wf[jj * 256 + o];
    for (int o = 0; o < 128; ++o) acc += Wr[(o * 128 + c) * 5 + 0] * Wf[jj * 256 + 128 + o];
  } else {
    int blkid = (kk - 128) >> 7;
    int gk = (blkid == 0) ? 1 : (blkid == 1) ? 3 : (blkid == 2) ? 2 : 4;
    int c = (kk - 128) & 127;
    for (int o = 0; o < 128; ++o) acc += Wr[(o * 128 + c) * 5 + gk] * Wf[jj * 256 + 128 + o];
  }
  Wt[j * 640 + kk] = f2bf(acc);
}

__global__ void k_bias(const float* __restrict__ bal, const float* __restrict__ bat,
                       const float* __restrict__ baf, const float* __restrict__ bbl,
                       const float* __restrict__ bbt, const float* __restrict__ bbf,
                       const float* __restrict__ Waf, const float* __restrict__ Wbf,
                       float* __restrict__ biasF) {
  int id = blockIdx.x * 256 + threadIdx.x;
  if (id >= 512) return;
  const float* Wf = (id < 256) ? Waf : Wbf;
  const float* bl = (id < 256) ? bal : bbl;
  const float* bt = (id < 256) ? bat : bbt;
  const float* bsf = (id < 256) ? baf : bbf;
  int jj = id & 255;
  float acc = bsf[jj];
  for (int o = 0; o < 128; ++o) acc += Wf[jj * 256 + o] * bl[o];
  for (int o = 0; o < 128; ++o) acc += Wf[jj * 256 + 128 + o] * bt[o];
  biasF[id] = acc;
}

// First-layer weights -> bf16, [side][j][c] row-major
__global__ void k_wt1(const float* __restrict__ Wa, const float* __restrict__ Wb,
                      uint16_t* __restrict__ W1bf) {
  int id = blockIdx.x * 256 + threadIdx.x;
  if (id >= 2 * 64 * 256) return;
  int side = id >> 14, r = id & 16383;
  W1bf[id] = f2bf(side ? Wb[r] : Wa[r]);
}

// ---------------- K1 (R7-exact): XA = [Wa@x0+ba | Wb@x1+bb] ----------------
__global__ __launch_bounds__(256) void k1_xa(
    const float* __restrict__ x0, const float* __restrict__ x1,
    const uint16_t* __restrict__ W1bf, const float* __restrict__ ba,
    const float* __restrict__ bb, uint16_t* __restrict__ XA) {
  __shared__ __align__(16) float Xs[3][32 * 128];    // 3 x 16 KB
  __shared__ __align__(16) uint16_t Bs[64 * 256];    // 32 KB
  int t = threadIdx.x;
  int side = blockIdx.y, b = blockIdx.z;
  int n0 = blockIdx.x * 128;
  const float* xin = (side ? x1 : x0) + (size_t)b * 256 * NEDGE + n0;
  const uint16_t* wsrc = W1bf + side * 64 * 256;

#pragma unroll
  for (int q = 0; q < 8; ++q) {
    int s = q * 256 + t;
    int j = s >> 5, pb = s & 31;
    int lb = pb ^ (j & 7);
    gload_lds16(wsrc + j * 256 + lb * 8, &Bs[s * 8]);
  }
#pragma unroll
  for (int c = 0; c < 2; ++c) {
#pragma unroll
    for (int q = 0; q < 4; ++q) {
      int s = q * 256 + t;
      int cl = s >> 5, pb = s & 31;
      int lb = pb ^ (((cl >> 3) & 3) << 2);
      gload_lds16(xin + (size_t)(c * 32 + cl) * NEDGE + lb * 4, &Xs[c][s * 4]);
    }
  }

  int wv = t >> 6, l = t & 63;
  int m = l & 15, g = l >> 4;
  int pcol[2];
#pragma unroll
  for (int nf = 0; nf < 2; ++nf) {
    int n = wv * 32 + nf * 16 + m;
    pcol[nf] = (((n >> 2) ^ (g << 2)) << 2) + (n & 3);
  }

  f32x4 acc[2][4];
  f32x4 zero = {0.f, 0.f, 0.f, 0.f};
#pragma unroll
  for (int nf = 0; nf < 2; ++nf)
#pragma unroll
    for (int jf = 0; jf < 4; ++jf) acc[nf][jf] = zero;

#pragma unroll
  for (int ks = 0; ks < 8; ++ks) {
    if (ks < 6) {
      const float* xc = xin + (size_t)(ks + 2) * 32 * NEDGE;
#pragma unroll
      for (int q = 0; q < 4; ++q) {
        int s = q * 256 + t;
        int cl = s >> 5, pb = s & 31;
        int lb = pb ^ (((cl >> 3) & 3) << 2);
        gload_lds16(xc + (size_t)cl * NEDGE + lb * 4, &Xs[(ks + 2) % 3][s * 4]);
      }
      VMCNT(8);
    } else if (ks == 6) {
      VMCNT(4);
    } else {
      VMCNT(0);
    }
    SCHEDB;
    __builtin_amdgcn_s_barrier();
    SCHEDB;

    const float* Xb = Xs[ks % 3];
    bf16x8 af[4];
#pragma unroll
    for (int jf = 0; jf < 4; ++jf) {
      int jloc = jf * 16 + m;
      int pbb = (ks * 4 + g) ^ (jloc & 7);
      af[jf] = *(const bf16x8*)&Bs[jloc * 256 + pbb * 8];
    }
#pragma unroll
    for (int nf = 0; nf < 2; ++nf) {
      const float* base = Xb + g * 8 * 128 + pcol[nf];
      float xv[8];
#pragma unroll
      for (int i = 0; i < 8; ++i) xv[i] = base[i * 128];
      union { bf16x8 v; uint32_t u[4]; } bx;
      bx.u[0] = packbf(xv[0], xv[1]);
      bx.u[1] = packbf(xv[2], xv[3]);
      bx.u[2] = packbf(xv[4], xv[5]);
      bx.u[3] = packbf(xv[6], xv[7]);
#pragma unroll
      for (int jf = 0; jf < 4; ++jf)
        acc[nf][jf] = __builtin_amdgcn_mfma_f32_16x16x32_bf16(af[jf], bx.v, acc[nf][jf], 0, 0, 0);
    }
    LGKM0;
    __builtin_amdgcn_s_barrier();
    SCHEDB;
  }

  const float* bias = side ? bb : ba;
  uint16_t* XAb = XA + (size_t)b * NEDGE * 128;
#pragma unroll
  for (int jf = 0; jf < 4; ++jf) {
    f32x4 bv = *(const f32x4*)(bias + jf * 16 + g * 4);
#pragma unroll
    for (int nf = 0; nf < 2; ++nf) {
      int n = n0 + wv * 32 + nf * 16 + m;
      uint2 o;
      o.x = packbf(acc[nf][jf][0] + bv[0], acc[nf][jf][1] + bv[1]);
      o.y = packbf(acc[nf][jf][2] + bv[2], acc[nf][jf][3] + bv[3]);
      *(uint2*)(XAb + (size_t)n * 128 + side * 64 + jf * 16 + g * 4) = o;
    }
  }
}

// ---------------- K23: fused gather+features+GEMM+stats, JT=128 col tile ----
// Same ledger as R13 but Bs chunks are 2 instr (16KB buffers). LDS = 70 KB
// -> 2 blocks/CU (the untested cell: occupancy WITHOUT losing double-buffer).
// Grid 2048 = 8 XCD x (64 row-tiles x 4 col-tiles), row-tile-major per XCD.
__global__ __launch_bounds__(512) void k23_gemm(
    const uint16_t* __restrict__ XAb, const int* __restrict__ gidx,
    const uint16_t* __restrict__ Wt, const float* __restrict__ biasF,
    uint16_t* __restrict__ Y, float* __restrict__ part) {
  __shared__ __align__(16) uint16_t As[2][128 * 64];    // 32 KB
  __shared__ __align__(16) uint16_t Bs2[2][128 * 64];   // 32 KB
  __shared__ int gi[512];                               // 2 KB
  __shared__ float sL[2][128][2];                       // 2 KB
  int t = threadIdx.x;
  int L = blockIdx.x;
  int xcd = L & 7, jz = L >> 3;            // jz in [0,256)
  int bx = xcd * 64 + (jz >> 2);           // row tile [0,512)
  int jbase = (jz & 3) * 128;              // col tile {0,128,256,384}
  int ebase = bx * 128;
  int wid = t >> 6, lane = t & 63;
  int wr = wid >> 2, wc = wid & 3;
  int m = lane & 15, g = lane >> 4;

  gi[t] = gidx[(size_t)ebase * 4 + t];
  __syncthreads();

  const int r0 = t >> 3, cc = t & 7;
  int iP13[2], iQ13[2], iP24[2], iQ24[2];
#pragma unroll
  for (int q2 = 0; q2 < 2; ++q2) {
    int r = r0 + q2 * 64;
    iP13[q2] = gi[r * 4 + 0]; iQ13[q2] = gi[r * 4 + 2];
    iP24[q2] = gi[r * 4 + 1]; iQ24[q2] = gi[r * 4 + 3];
  }

  uint4 grP[2][2], grQ[2][2];  // [chunk parity][slot]

#define ISSUE_GATH(v)                                                           \
  do {                                                                          \
    const int coffv = ((v) & 1) * 64;                                           \
    const int pr = ((v) - 2) >> 2;                                              \
    _Pragma("unroll")                                                           \
    for (int q2 = 0; q2 < 2; ++q2) {                                            \
      int ip = pr ? iP24[q2] : iP13[q2];                                        \
      int iq = pr ? iQ24[q2] : iQ13[q2];                                        \
      grP[(v) & 1][q2] = *(const uint4*)(XAb + (size_t)ip * 128 + coffv + cc * 8); \
      grQ[(v) & 1][q2] = *(const uint4*)(XAb + (size_t)iq * 128 + coffv + cc * 8); \
    }                                                                           \
  } while (0)

#define ISSUE_BS(s_)                                                            \
  do {                                                                          \
    _Pragma("unroll")                                                           \
    for (int q = 0; q < 2; ++q) {                                               \
      int slot = q * 512 + t; int r = slot >> 3, c16 = slot & 7;                \
      gload_lds16(Wt + (size_t)(jbase + r) * 640 + (s_) * 64 + (c16 ^ (r & 7)) * 8, \
                  &Bs2[(s_) & 1][slot * 8]);                                    \
    }                                                                           \
  } while (0)

#define ISSUE_AS_DIRECT(s_)                                                     \
  do {                                                                          \
    _Pragma("unroll")                                                           \
    for (int q = 0; q < 2; ++q) {                                               \
      int slot = q * 512 + t; int r = slot >> 3, c16 = slot & 7;                \
      gload_lds16(XAb + (size_t)(ebase + r) * 128 + (s_) * 64 + (c16 ^ (r & 7)) * 8, \
                  &As[(s_) & 1][slot * 8]);                                     \
    }                                                                           \
  } while (0)

  // prologue: G(2):4 (oldest), then A0:2, B0:2, A1:2, B1:2  (12 outstanding)
  ISSUE_GATH(2);
  ISSUE_AS_DIRECT(0);
  ISSUE_BS(0);
  ISSUE_AS_DIRECT(1);
  ISSUE_BS(1);

  f32x4 acc[4][2];  // [edge-frag r][j-frag cf]
  f32x4 zero = {0.f, 0.f, 0.f, 0.f};
#pragma unroll
  for (int r = 0; r < 4; ++r)
#pragma unroll
    for (int c = 0; c < 2; ++c) acc[r][c] = zero;

#pragma unroll
  for (int u = 0; u < 10; ++u) {
    const int su = u + 1;  // chunk being ds_written this iter
    if (su >= 2 && su <= 9) {
      if (u == 1) { VMCNT(4); } else { VMCNT(2); }  // gather regs for su ready
      const int sum_op = (((su - 2) >> 1) & 1) == 0;
      const int bi = su & 1;
#pragma unroll
      for (int q2 = 0; q2 < 2; ++q2) {
        int r = r0 + q2 * 64;
        uint4 P = grP[bi][q2], Q = grQ[bi][q2];
        uint4 R;
        if (sum_op) {
          R.x = packbf(bflo(P.x) + bflo(Q.x), bfhi(P.x) + bfhi(Q.x));
          R.y = packbf(bflo(P.y) + bflo(Q.y), bfhi(P.y) + bfhi(Q.y));
          R.z = packbf(bflo(P.z) + bflo(Q.z), bfhi(P.z) + bfhi(Q.z));
          R.w = packbf(bflo(P.w) + bflo(Q.w), bfhi(P.w) + bfhi(Q.w));
        } else {
          R.x = packbf(fabsf(bflo(P.x) - bflo(Q.x)), fabsf(bfhi(P.x) - bfhi(Q.x)));
          R.y = packbf(fabsf(bflo(P.y) - bflo(Q.y)), fabsf(bfhi(P.y) - bfhi(Q.y)));
          R.z = packbf(fabsf(bflo(P.z) - bflo(Q.z)), fabsf(bfhi(P.z) - bfhi(Q.z)));
          R.w = packbf(fabsf(bflo(P.w) - bflo(Q.w)), fabsf(bfhi(P.w) - bfhi(Q.w)));
        }
        *(uint4*)&As[bi][(r * 8 + (cc ^ (r & 7))) * 8] = R;
      }
    }
    if (u + 2 >= 3 && u + 2 <= 9) ISSUE_GATH(u + 2);
    if (su >= 2 && su <= 9) ISSUE_BS(su);
    // tail wait: chunk u's As/Bs landed; keep G(next)+Bs(next) in flight
    if (u == 0) { VMCNT_LGKM0(4); }
    else if (u <= 7) { VMCNT_LGKM0(6); }
    else if (u == 8) { VMCNT_LGKM0(2); }
    else { VMCNT_LGKM0(0); }
    SCHEDB;
    __builtin_amdgcn_s_barrier();
    SCHEDB;

    const uint16_t* Ab = As[u & 1];
    const uint16_t* Bb = Bs2[u & 1];
#pragma unroll
    for (int kit = 0; kit < 2; ++kit) {
      bf16x8 af[4], bf[2];
#pragma unroll
      for (int r = 0; r < 4; ++r) {
        int row = wr * 64 + r * 16 + m;
        af[r] = *(const bf16x8*)&Ab[row * 64 + ((kit * 4 + g) ^ (m & 7)) * 8];
      }
#pragma unroll
      for (int cf = 0; cf < 2; ++cf) {
        int row = wc * 32 + cf * 16 + m;
        bf[cf] = *(const bf16x8*)&Bb[row * 64 + ((kit * 4 + g) ^ (m & 7)) * 8];
      }
      // swapped: A=Wt (M=j), B=edges (N=edge) -> D[j][edge]
#pragma unroll
      for (int r = 0; r < 4; ++r)
#pragma unroll
        for (int cf = 0; cf < 2; ++cf)
          acc[r][cf] = __builtin_amdgcn_mfma_f32_16x16x32_bf16(bf[cf], af[r], acc[r][cf], 0, 0, 0);
    }
    __builtin_amdgcn_s_barrier();
    SCHEDB;
  }
#undef ISSUE_GATH
#undef ISSUE_BS
#undef ISSUE_AS_DIRECT

  // epilogue: D[j][edge]: lane&15 = edge, regs = 4 consecutive j (g*4+q)
  float s1[2][4], s2[2][4];
#pragma unroll
  for (int cf = 0; cf < 2; ++cf)
#pragma unroll
    for (int q = 0; q < 4; ++q) { s1[cf][q] = 0.f; s2[cf][q] = 0.f; }

#pragma unroll
  for (int cf = 0; cf < 2; ++cf) {
    f32x4 bv = *(const f32x4*)(biasF + jbase + wc * 32 + cf * 16 + g * 4);
#pragma unroll
    for (int r = 0; r < 4; ++r) {
      int eg = ebase + wr * 64 + r * 16 + m;
      float v0 = acc[r][cf][0] + bv[0];
      float v1 = acc[r][cf][1] + bv[1];
      float v2 = acc[r][cf][2] + bv[2];
      float v3 = acc[r][cf][3] + bv[3];
      s1[cf][0] += v0; s2[cf][0] += v0 * v0;
      s1[cf][1] += v1; s2[cf][1] += v1 * v1;
      s1[cf][2] += v2; s2[cf][2] += v2 * v2;
      s1[cf][3] += v3; s2[cf][3] += v3 * v3;
      uint2 o;
      o.x = packbf(v0, v1);
      o.y = packbf(v2, v3);
      *(uint2*)(Y + (size_t)eg * 512 + jbase + wc * 32 + cf * 16 + g * 4) = o;
    }
  }
#pragma unroll
  for (int cf = 0; cf < 2; ++cf)
#pragma unroll
    for (int q = 0; q < 4; ++q) {
#pragma unroll
      for (int off = 1; off < 16; off <<= 1) {
        s1[cf][q] += __shfl_xor(s1[cf][q], off);
        s2[cf][q] += __shfl_xor(s2[cf][q], off);
      }
    }
  if (m == 0) {
#pragma unroll
    for (int cf = 0; cf < 2; ++cf)
#pragma unroll
      for (int q = 0; q < 4; ++q) {
        int jl = wc * 32 + cf * 16 + g * 4 + q;   // [0,128)
        sL[wr][jl][0] = s1[cf][q];
        sL[wr][jl][1] = s2[cf][q];
      }
  }
  __syncthreads();
  if (t < 128) {
    float a1 = sL[0][t][0] + sL[1][t][0];
    float a2 = sL[0][t][1] + sL[1][t][1];
    float* p = part + ((size_t)bx * 512 + jbase + t) * 2;
    p[0] = a1; p[1] = a2;
  }
}

// ---------------- K3b2: finalize per-column mean/rsqrt ----------------
__global__ void k3b2(const float* __restrict__ part, float* __restrict__ statF) {
  int col = blockIdx.x, t = threadIdx.x;
  float s1 = 0, s2 = 0;
  for (int k = t; k < 512; k += 128) {
    const float* p = part + ((size_t)k * 512 + col) * 2;
    s1 += p[0]; s2 += p[1];
  }
  for (int off = 32; off; off >>= 1) { s1 += __shfl_down(s1, off); s2 += __shfl_down(s2, off); }
  __shared__ float sh[4];
  if ((t & 63) == 0) { sh[(t >> 6) * 2] = s1; sh[(t >> 6) * 2 + 1] = s2; }
  __syncthreads();
  if (t == 0) {
    s1 = sh[0] + sh[2]; s2 = sh[1] + sh[3];
    float mean = s1 * (1.0f / 65536.0f);
    float var = s2 * (1.0f / 65536.0f) - mean * mean;
    statF[col * 2] = mean;
    statF[col * 2 + 1] = rsqrtf(var + 1e-5f);
  }
}

// ---------------- K4 (R7-exact): gate + blend, channel-major out ----------------
__global__ __launch_bounds__(256) void k4_final(
    const uint16_t* __restrict__ Y, const float* __restrict__ statF,
    const float* __restrict__ x0b, const float* __restrict__ x1b,
    float* __restrict__ outb) {
  __shared__ float W0[128][65];
  __shared__ float mA[128], rA[128], mB[128], rB[128];
  int t = threadIdx.x;
  int n0 = blockIdx.x * 64;
  int ch = blockIdx.y;
  if (t < 128) {
    mA[t] = statF[(ch * 128 + t) * 2];
    rA[t] = statF[(ch * 128 + t) * 2 + 1];
  } else {
    int q = t - 128;
    mB[q] = statF[(256 + ch * 128 + q) * 2];
    rB[q] = statF[(256 + ch * 128 + q) * 2 + 1];
  }
  __syncthreads();
  const char* Ybase = (const char*)Y;
  for (int i = t; i < 64 * 64; i += 256) {
    int row = i >> 6, cp = i & 63;
    const char* yr = Ybase + (size_t)(n0 + row) * 1024;
    uint32_t ya2 = *(const uint32_t*)(yr + ch * 256 + cp * 4);
    uint32_t yb2 = *(const uint32_t*)(yr + 512 + ch * 256 + cp * 4);
    int c0 = 2 * cp, c1 = 2 * cp + 1;
    float wa0 = sigm((bflo(ya2) - mA[c0]) * rA[c0]);
    float wa1 = sigm((bfhi(ya2) - mA[c1]) * rA[c1]);
    float wb0 = sigm((bflo(yb2) - mB[c0]) * rB[c0]);
    float wb1 = sigm((bfhi(yb2) - mB[c1]) * rB[c1]);
    W0[c0][row] = sigm(wa0 - wb0);
    W0[c1][row] = sigm(wa1 - wb1);
  }
  __syncthreads();
  int nn = t & 63, cg = t >> 6;
  for (int cc2 = cg; cc2 < 128; cc2 += 4) {
    int c = ch * 128 + cc2;
    size_t gidx2 = (size_t)c * NEDGE + n0 + nn;
    float w0 = W0[cc2][nn];
    outb[gidx2] = x0b[gidx2] * w0 + x1b[gidx2] * (1.0f - w0);
  }
}

extern "C" void kernel_launch(void* const* d_in, const int* in_sizes, int n_in,
                              void* d_out, int out_size, void* d_ws, size_t ws_size,
                              hipStream_t stream) {
  const float* x0 = (const float*)d_in[0];
  const float* x1 = (const float*)d_in[1];
  const int* gemm = (const int*)d_in[2];
  const float* Wa = (const float*)d_in[3];
  const float* ba = (const float*)d_in[4];
  const float* Wb = (const float*)d_in[5];
  const float* bb = (const float*)d_in[6];
  const float* Wal = (const float*)d_in[7];
  const float* bal = (const float*)d_in[8];
  const float* Wbl = (const float*)d_in[9];
  const float* bbl = (const float*)d_in[10];
  const float* Wat = (const float*)d_in[11];
  const float* bat = (const float*)d_in[12];
  const float* Wbt = (const float*)d_in[13];
  const float* bbt = (const float*)d_in[14];
  const float* Waf = (const float*)d_in[15];
  const float* baf = (const float*)d_in[16];
  const float* Wbf = (const float*)d_in[17];
  const float* bbf = (const float*)d_in[18];
  float* out = (float*)d_out;

  char* ws = (char*)d_ws;
  uint16_t* XA   = (uint16_t*)ws;                    // 33,554,432 B
  uint16_t* Yb   = (uint16_t*)(ws + 33554432);       // 67,108,864 B (per-batch reuse)
  uint16_t* Wt   = (uint16_t*)(ws + 100663296);      // 655,360 B
  uint16_t* W1bf = (uint16_t*)(ws + 101318656);      // 65,536 B
  float*    biasF= (float*)(ws + 101384192);         // 2,048 B
  float*    part = (float*)(ws + 101386240);         // 2,097,152 B (per-batch reuse)
  float*    statF= (float*)(ws + 103483392);         // 8,192 B

  k_compose<<<dim3(1280), dim3(256), 0, stream>>>(Wal, Wbl, Wat, Wbt, Waf, Wbf, Wt);
  k_bias<<<dim3(2), dim3(256), 0, stream>>>(bal, bat, baf, bbl, bbt, bbf, Waf, Wbf, biasF);
  k_wt1<<<dim3(128), dim3(256), 0, stream>>>(Wa, Wb, W1bf);
  k1_xa<<<dim3(512, 2, 2), dim3(256), 0, stream>>>(x0, x1, W1bf, ba, bb, XA);

  for (int b = 0; b < 2; ++b) {
    const uint16_t* XAb = XA + (size_t)b * NEDGE * 128;
    k23_gemm<<<dim3(2048), dim3(512), 0, stream>>>(
        XAb, gemm + (size_t)b * NEDGE * 4, Wt, biasF, Yb, part);
    k3b2<<<dim3(512), dim3(128), 0, stream>>>(part, statF + b * 1024);
    k4_final<<<dim3(1024, 2), dim3(256), 0, stream>>>(
        Yb, statF + b * 1024, x0 + (size_t)b * 256 * NEDGE,
        x1 + (size_t)b * 256 * NEDGE, out + (size_t)b * 256 * NEDGE);
  }
}